// Round 1
// baseline (733.433 us; speedup 1.0000x reference)
//
#include <hip/hip_runtime.h>
#include <hip/hip_cooperative_groups.h>
#include <math.h>

namespace cg = cooperative_groups;

#define NROWS 8192
#define FIN   512
#define FOUT  256
#define NCHUNK 512
#define CHROWS 16   // NROWS / NCHUNK

typedef _Float16 f16;
typedef _Float16 f16x8 __attribute__((ext_vector_type(8)));
typedef float    f32x4 __attribute__((ext_vector_type(4)));

// ---------------- workspace layout (shared host/device) ----------------
constexpr size_t AL(size_t v) { return (v + 255) & ~(size_t)255; }
constexpr size_t SZ_XH  = (size_t)NROWS * FIN * 2;
constexpr size_t SZ_WT  = (size_t)FOUT * FIN * 2;
constexpr size_t SZ_H   = (size_t)NROWS * FOUT * 2;
constexpr size_t SZ_PS  = (size_t)(NROWS + 1) * FOUT * 2;
constexpr size_t SZ_FG  = (size_t)2 * NROWS * 4;
constexpr size_t SZ_I   = (size_t)NROWS * 4;
constexpr size_t SZ_C   = (size_t)NCHUNK * FOUT * 4;
constexpr size_t SZ_CS  = (size_t)NCHUNK * 4;
constexpr size_t SZ_S1S = (size_t)(NROWS + 1) * 4;

constexpr size_t OFF_XH   = 0;
constexpr size_t OFF_WT   = OFF_XH   + AL(SZ_XH);
constexpr size_t OFF_H    = OFF_WT   + AL(SZ_WT);
constexpr size_t OFF_P0   = OFF_H    + AL(SZ_H);
constexpr size_t OFF_S1   = OFF_P0   + AL(SZ_PS);
constexpr size_t OFF_FG   = OFF_S1   + AL(SZ_PS);
constexpr size_t OFF_GS   = OFF_FG   + AL(SZ_FG);
constexpr size_t OFF_PERM = OFF_GS   + AL(SZ_I);
constexpr size_t OFF_N0   = OFF_PERM + AL(SZ_I);
constexpr size_t OFF_C0   = OFF_N0   + AL(SZ_I);
constexpr size_t OFF_C1   = OFF_C0   + AL(SZ_C);
constexpr size_t OFF_O0   = OFF_C1   + AL(SZ_C);
constexpr size_t OFF_O1   = OFF_O0   + AL(SZ_C);
constexpr size_t OFF_C1S  = OFF_O1   + AL(SZ_C);
constexpr size_t OFF_O1S  = OFF_C1S  + AL(SZ_CS);
constexpr size_t OFF_S1S  = OFF_O1S  + AL(SZ_CS);

// ---------------- LDS union (max = gemm phase: 35,840 B -> 2+ blocks/CU) ----
union SmemU {
    struct { f16 As[64][136]; f16 Bs[64][136]; float sf[2][64]; float sg[2][64]; } g;
    struct { int part[16][16]; } r;
    struct { int p[CHROWS]; float wl[CHROWS]; } c;
    struct { float sb[256]; } s;
};

// =======================================================================
// MEGA: whole pipeline, one cooperative launch, 6 grid syncs
// =======================================================================
__global__ __launch_bounds__(256, 2) void mega(const float* __restrict__ x,
                                               const float* __restrict__ W,
                                               const float* __restrict__ a,
                                               float* __restrict__ out,
                                               char* __restrict__ ws) {
    __shared__ SmemU sm;
    cg::grid_group grid = cg::this_grid();
    const int b = blockIdx.x, tid = threadIdx.x;

    f16*   xh   = (f16*)(ws + OFF_XH);
    f16*   Wt   = (f16*)(ws + OFF_WT);
    f16*   hb   = (f16*)(ws + OFF_H);
    f16*   P0b  = (f16*)(ws + OFF_P0);
    f16*   S1b  = (f16*)(ws + OFF_S1);
    float* fArr = (float*)(ws + OFF_FG);
    float* gArr = fArr + NROWS;
    float* gs   = (float*)(ws + OFF_GS);
    int*   perm = (int*)(ws + OFF_PERM);
    int*   n0arr= (int*)(ws + OFF_N0);
    float* c0   = (float*)(ws + OFF_C0);
    float* c1   = (float*)(ws + OFF_C1);
    float* o0   = (float*)(ws + OFF_O0);
    float* o1   = (float*)(ws + OFF_O1);
    float* c1s  = (float*)(ws + OFF_C1S);
    float* o1s  = (float*)(ws + OFF_O1S);
    float* S1s  = (float*)(ws + OFF_S1S);

    // ---- P0: prep (x->f16; W->Wt transposed f16; zero f/g) ----
    if (b < 256) {
        const size_t base = (size_t)b * 16384;
#pragma unroll 4
        for (int i = 0; i < 16; ++i) {
            const size_t idx = base + (size_t)i * 1024 + tid * 4;
            float4 v = *(const float4*)&x[idx];
            union { f16 h4[4]; ushort4 u; } cv;
            cv.h4[0] = (f16)v.x; cv.h4[1] = (f16)v.y;
            cv.h4[2] = (f16)v.z; cv.h4[3] = (f16)v.w;
            *(ushort4*)&xh[idx] = cv.u;
        }
    } else {
        const int n = b - 256;
        Wt[(size_t)n * FIN + tid]       = (f16)W[(size_t)tid * FOUT + n];
        Wt[(size_t)n * FIN + tid + 256] = (f16)W[(size_t)(tid + 256) * FOUT + n];
        if (n < 64) fArr[n * 256 + tid] = 0.f;   // zeros both f and g
    }
    __threadfence();
    grid.sync();

    // ---- P1: GEMM h = x@W (f16 MFMA, BK=128) + f/g partials ----
    {
        const int n0 = (b & 3) * 64;
        const int m0 = (b >> 2) * 64;
        const int srow = tid >> 2, sseg = (tid & 3) * 8;
        const int w = tid >> 6, lane = tid & 63;
        const int wm = (w & 1) * 32, wn = (w >> 1) * 32;
        const int l15 = lane & 15, quad = lane >> 4;

        f16x8 pa[4], pb[4];
#pragma unroll
        for (int j = 0; j < 4; ++j) {
            pa[j] = *(const f16x8*)&xh[(size_t)(m0 + srow) * FIN + j * 32 + sseg];
            pb[j] = *(const f16x8*)&Wt[(size_t)(n0 + srow) * FIN + j * 32 + sseg];
        }

        f32x4 acc[2][2] = {};
        for (int k0 = 0; k0 < FIN; k0 += 128) {
            __syncthreads();
#pragma unroll
            for (int j = 0; j < 4; ++j) {
                *(f16x8*)&sm.g.As[srow][j * 32 + sseg] = pa[j];
                *(f16x8*)&sm.g.Bs[srow][j * 32 + sseg] = pb[j];
            }
            __syncthreads();
            if (k0 + 128 < FIN) {
#pragma unroll
                for (int j = 0; j < 4; ++j) {
                    pa[j] = *(const f16x8*)&xh[(size_t)(m0 + srow) * FIN + k0 + 128 + j * 32 + sseg];
                    pb[j] = *(const f16x8*)&Wt[(size_t)(n0 + srow) * FIN + k0 + 128 + j * 32 + sseg];
                }
            }
#pragma unroll
            for (int kk = 0; kk < 4; ++kk) {
                f16x8 af[2], bf[2];
#pragma unroll
                for (int ti = 0; ti < 2; ++ti)
                    af[ti] = *(const f16x8*)&sm.g.As[wm + ti * 16 + l15][kk * 32 + quad * 8];
#pragma unroll
                for (int tj = 0; tj < 2; ++tj)
                    bf[tj] = *(const f16x8*)&sm.g.Bs[wn + tj * 16 + l15][kk * 32 + quad * 8];
#pragma unroll
                for (int ti = 0; ti < 2; ++ti)
#pragma unroll
                    for (int tj = 0; tj < 2; ++tj)
                        acc[ti][tj] = __builtin_amdgcn_mfma_f32_16x16x32_f16(af[ti], bf[tj], acc[ti][tj], 0, 0, 0);
            }
        }
#pragma unroll
        for (int ti = 0; ti < 2; ++ti)
#pragma unroll
            for (int tj = 0; tj < 2; ++tj) {
                const int col = n0 + wn + tj * 16 + l15;
#pragma unroll
                for (int r = 0; r < 4; ++r) {
                    const int row = m0 + wm + ti * 16 + quad * 4 + r;
                    hb[(size_t)row * FOUT + col] = (f16)acc[ti][tj][r];
                }
            }
        const float a1c0 = a[n0 + wn + l15];
        const float a1c1 = a[n0 + wn + 16 + l15];
        const float a2c0 = a[FOUT + n0 + wn + l15];
        const float a2c1 = a[FOUT + n0 + wn + 16 + l15];
        const int wnIdx = w >> 1;
#pragma unroll
        for (int ti = 0; ti < 2; ++ti) {
            float pf[4], pg[4];
#pragma unroll
            for (int r = 0; r < 4; ++r) {
                pf[r] = acc[ti][0][r] * a1c0 + acc[ti][1][r] * a1c1;
                pg[r] = acc[ti][0][r] * a2c0 + acc[ti][1][r] * a2c1;
            }
#pragma unroll
            for (int off = 8; off >= 1; off >>= 1)
#pragma unroll
                for (int r = 0; r < 4; ++r) {
                    pf[r] += __shfl_xor(pf[r], off, 16);
                    pg[r] += __shfl_xor(pg[r], off, 16);
                }
            if (l15 == 0)
#pragma unroll
                for (int r = 0; r < 4; ++r) {
                    sm.g.sf[wnIdx][wm + ti * 16 + quad * 4 + r] = pf[r];
                    sm.g.sg[wnIdx][wm + ti * 16 + quad * 4 + r] = pg[r];
                }
        }
        __syncthreads();
        if (tid < 64) {
            atomicAdd(&fArr[m0 + tid], sm.g.sf[0][tid] + sm.g.sf[1][tid]);
            atomicAdd(&gArr[m0 + tid], sm.g.sg[0][tid] + sm.g.sg[1][tid]);
        }
    }
    __threadfence();
    grid.sync();

    // ---- P2: rank + scatter (512 blocks x 16 j, 16 segments of 512) ----
    {
        const int jl = tid & 15, seg = tid >> 4;
        const int j = b * 16 + jl;
        const float gj = gArr[j];
        const int base = seg * 512;
        int cnt = 0;
#pragma unroll 4
        for (int r = 0; r < 512; r += 4) {
            const float4 v = *(const float4*)&gArr[base + r];
            const int i0 = base + r;
            cnt += (v.x < gj) || (v.x == gj && (i0 + 0) < j);
            cnt += (v.y < gj) || (v.y == gj && (i0 + 1) < j);
            cnt += (v.z < gj) || (v.z == gj && (i0 + 2) < j);
            cnt += (v.w < gj) || (v.w == gj && (i0 + 3) < j);
        }
        sm.r.part[seg][jl] = cnt;
        __syncthreads();
        if (seg == 0) {
            int rank = 0;
#pragma unroll
            for (int ss = 0; ss < 16; ++ss) rank += sm.r.part[ss][jl];
            gs[rank] = gj;
            perm[rank] = j;
        }
    }
    __threadfence();
    grid.sync();

    // ---- P3: per-chunk sums (c0, c1, c1s) ----
    {
        const int base = b * CHROWS;
        if (tid < CHROWS) {
            sm.c.p[tid] = perm[base + tid];
            sm.c.wl[tid] = expf(gs[base + tid] - gs[NROWS - 1]);
        }
        __syncthreads();
        float s0 = 0.f, s1v = 0.f;
        for (int r = 0; r < CHROWS; ++r) {
            float v = (float)hb[(size_t)sm.c.p[r] * FOUT + tid];
            s0 += v;
            s1v += sm.c.wl[r] * v;
        }
        c0[b * FOUT + tid] = s0;
        c1[b * FOUT + tid] = s1v;
        if (tid == 0) {
            float t2 = 0.f;
            for (int r = 0; r < CHROWS; ++r) t2 += sm.c.wl[r];
            c1s[b] = t2;
        }
    }
    __threadfence();
    grid.sync();

    // ---- P4: column scans (blocks 0-255) + n0 binary searches (256-287) ----
    if (b < 256) {
        const int col = b;
        {   // exclusive prefix over c0 column
            const float e0 = c0[(2 * tid) * FOUT + col];
            const float e1 = c0[(2 * tid + 1) * FOUT + col];
            const float local = e0 + e1;
            sm.s.sb[tid] = local;
            __syncthreads();
            for (int off = 1; off < 256; off <<= 1) {
                float add = (tid >= off) ? sm.s.sb[tid - off] : 0.f;
                __syncthreads();
                sm.s.sb[tid] += add;
                __syncthreads();
            }
            const float ex = sm.s.sb[tid] - local;
            o0[(2 * tid) * FOUT + col] = ex;
            o0[(2 * tid + 1) * FOUT + col] = ex + e0;
        }
        __syncthreads();
        {   // exclusive suffix over c1 column
            const float e0 = c1[(2 * tid) * FOUT + col];
            const float e1 = c1[(2 * tid + 1) * FOUT + col];
            const float local = e0 + e1;
            sm.s.sb[tid] = local;
            __syncthreads();
            for (int off = 1; off < 256; off <<= 1) {
                float add = (tid + off < 256) ? sm.s.sb[tid + off] : 0.f;
                __syncthreads();
                sm.s.sb[tid] += add;
                __syncthreads();
            }
            const float exs = sm.s.sb[tid] - local;
            o1[(2 * tid) * FOUT + col] = exs + e1;
            o1[(2 * tid + 1) * FOUT + col] = exs;
        }
        if (b == 0) {   // exclusive suffix over c1s (scalar)
            __syncthreads();
            const float e0 = c1s[2 * tid];
            const float e1 = c1s[2 * tid + 1];
            const float local = e0 + e1;
            sm.s.sb[tid] = local;
            __syncthreads();
            for (int off = 1; off < 256; off <<= 1) {
                float add = (tid + off < 256) ? sm.s.sb[tid + off] : 0.f;
                __syncthreads();
                sm.s.sb[tid] += add;
                __syncthreads();
            }
            const float exs = sm.s.sb[tid] - local;
            o1s[2 * tid] = exs + e1;
            o1s[2 * tid + 1] = exs;
        }
    } else if (b < 288) {
        const int i = (b - 256) * 256 + tid;   // 0..8191
        const float tt = -fArr[i];
        int lo = 0, hi = NROWS;
        while (lo < hi) {
            int mid = (lo + hi) >> 1;
            if (gs[mid] <= tt) lo = mid + 1; else hi = mid;
        }
        n0arr[i] = lo;
    }
    __threadfence();
    grid.sync();

    // ---- P5: element-granular P0 / S1 / S1s ----
    {
        const int base = b * CHROWS;
        if (tid < CHROWS) {
            sm.c.p[tid] = perm[base + tid];
            sm.c.wl[tid] = expf(gs[base + tid] - gs[NROWS - 1]);
        }
        __syncthreads();
        float run0 = o0[b * FOUT + tid];
        for (int r = 0; r < CHROWS; ++r) {
            P0b[(size_t)(base + r) * FOUT + tid] = (f16)run0;
            run0 += (float)hb[(size_t)sm.c.p[r] * FOUT + tid];
        }
        float run1 = o1[b * FOUT + tid];
        for (int r = CHROWS - 1; r >= 0; --r) {
            run1 += sm.c.wl[r] * (float)hb[(size_t)sm.c.p[r] * FOUT + tid];
            S1b[(size_t)(base + r) * FOUT + tid] = (f16)run1;
        }
        if (tid == 0) {
            float rs = o1s[b];
            for (int r = CHROWS - 1; r >= 0; --r) { rs += sm.c.wl[r]; S1s[base + r] = rs; }
        }
        if (b == NCHUNK - 1) {
            P0b[(size_t)NROWS * FOUT + tid] = (f16)run0;
            S1b[(size_t)NROWS * FOUT + tid] = (f16)0.f;
            if (tid == 0) S1s[NROWS] = 0.f;
        }
    }
    __threadfence();
    grid.sync();

    // ---- P6: streaming combine + ELU (16 rows / block) ----
    {
        const float gm = gs[NROWS - 1];
#pragma unroll 4
        for (int rr = 0; rr < 16; ++rr) {
            const int i = b * 16 + rr;
            const float fi = fArr[i];
            const int n0i = n0arr[i];
            const float m = fmaxf(0.f, fi + gm);
            const float A = expf(-m);
            const float B = expf(fi + gm - m);
            const float denom = A * (float)n0i + B * S1s[n0i];
            const float numer = A * (float)P0b[(size_t)n0i * FOUT + tid]
                              + B * (float)S1b[(size_t)n0i * FOUT + tid];
            const float v = numer / denom;
            out[(size_t)i * FOUT + tid] = v > 0.f ? v : expm1f(v);
        }
    }
}

// =======================================================================
// Fallback path: the proven 7-kernel pipeline (unchanged), used only if
// the cooperative enqueue is rejected (e.g. capture incompatibility).
// =======================================================================
__global__ __launch_bounds__(256) void prep(const float* __restrict__ x,
                                            const float* __restrict__ W,
                                            f16* __restrict__ xh,
                                            f16* __restrict__ Wt,
                                            float* __restrict__ fg) {
    const int b = blockIdx.x, t = threadIdx.x;
    if (b < 256) {
        const size_t base = (size_t)b * 16384;
#pragma unroll 4
        for (int i = 0; i < 16; ++i) {
            const size_t idx = base + (size_t)i * 1024 + t * 4;
            float4 v = *(const float4*)&x[idx];
            union { f16 h[4]; ushort4 u; } cv;
            cv.h[0] = (f16)v.x; cv.h[1] = (f16)v.y;
            cv.h[2] = (f16)v.z; cv.h[3] = (f16)v.w;
            *(ushort4*)&xh[idx] = cv.u;
        }
    } else {
        const int n = b - 256;
        Wt[(size_t)n * FIN + t]       = (f16)W[(size_t)t * FOUT + n];
        Wt[(size_t)n * FIN + t + 256] = (f16)W[(size_t)(t + 256) * FOUT + n];
        if (n < 64) fg[n * 256 + t] = 0.f;
    }
}

__global__ __launch_bounds__(256) void gemm_fg(const f16* __restrict__ xh,
                                               const f16* __restrict__ Wt,
                                               const float* __restrict__ a,
                                               f16* __restrict__ h,
                                               float* __restrict__ f,
                                               float* __restrict__ g) {
    __shared__ __align__(16) f16 As[64][136];
    __shared__ __align__(16) f16 Bs[64][136];
    __shared__ float sf[2][64], sg[2][64];
    const int tid = threadIdx.x;
    const int n0 = blockIdx.x * 64;
    const int m0 = blockIdx.y * 64;
    const int srow = tid >> 2, sseg = (tid & 3) * 8;
    const int w = tid >> 6, lane = tid & 63;
    const int wm = (w & 1) * 32, wn = (w >> 1) * 32;
    const int l15 = lane & 15, quad = lane >> 4;

    f16x8 pa[4], pb[4];
#pragma unroll
    for (int j = 0; j < 4; ++j) {
        pa[j] = *(const f16x8*)&xh[(size_t)(m0 + srow) * FIN + j * 32 + sseg];
        pb[j] = *(const f16x8*)&Wt[(size_t)(n0 + srow) * FIN + j * 32 + sseg];
    }

    f32x4 acc[2][2] = {};
    for (int k0 = 0; k0 < FIN; k0 += 128) {
        __syncthreads();
#pragma unroll
        for (int j = 0; j < 4; ++j) {
            *(f16x8*)&As[srow][j * 32 + sseg] = pa[j];
            *(f16x8*)&Bs[srow][j * 32 + sseg] = pb[j];
        }
        __syncthreads();
        if (k0 + 128 < FIN) {
#pragma unroll
            for (int j = 0; j < 4; ++j) {
                pa[j] = *(const f16x8*)&xh[(size_t)(m0 + srow) * FIN + k0 + 128 + j * 32 + sseg];
                pb[j] = *(const f16x8*)&Wt[(size_t)(n0 + srow) * FIN + k0 + 128 + j * 32 + sseg];
            }
        }
#pragma unroll
        for (int kk = 0; kk < 4; ++kk) {
            f16x8 af[2], bf[2];
#pragma unroll
            for (int ti = 0; ti < 2; ++ti)
                af[ti] = *(const f16x8*)&As[wm + ti * 16 + l15][kk * 32 + quad * 8];
#pragma unroll
            for (int tj = 0; tj < 2; ++tj)
                bf[tj] = *(const f16x8*)&Bs[wn + tj * 16 + l15][kk * 32 + quad * 8];
#pragma unroll
            for (int ti = 0; ti < 2; ++ti)
#pragma unroll
                for (int tj = 0; tj < 2; ++tj)
                    acc[ti][tj] = __builtin_amdgcn_mfma_f32_16x16x32_f16(af[ti], bf[tj], acc[ti][tj], 0, 0, 0);
        }
    }
#pragma unroll
    for (int ti = 0; ti < 2; ++ti)
#pragma unroll
        for (int tj = 0; tj < 2; ++tj) {
            const int col = n0 + wn + tj * 16 + l15;
#pragma unroll
            for (int r = 0; r < 4; ++r) {
                const int row = m0 + wm + ti * 16 + quad * 4 + r;
                h[(size_t)row * FOUT + col] = (f16)acc[ti][tj][r];
            }
        }
    const float a1c0 = a[n0 + wn + l15];
    const float a1c1 = a[n0 + wn + 16 + l15];
    const float a2c0 = a[FOUT + n0 + wn + l15];
    const float a2c1 = a[FOUT + n0 + wn + 16 + l15];
    const int wnIdx = w >> 1;
#pragma unroll
    for (int ti = 0; ti < 2; ++ti) {
        float pf[4], pg[4];
#pragma unroll
        for (int r = 0; r < 4; ++r) {
            pf[r] = acc[ti][0][r] * a1c0 + acc[ti][1][r] * a1c1;
            pg[r] = acc[ti][0][r] * a2c0 + acc[ti][1][r] * a2c1;
        }
#pragma unroll
        for (int off = 8; off >= 1; off >>= 1)
#pragma unroll
            for (int r = 0; r < 4; ++r) {
                pf[r] += __shfl_xor(pf[r], off, 16);
                pg[r] += __shfl_xor(pg[r], off, 16);
            }
        if (l15 == 0)
#pragma unroll
            for (int r = 0; r < 4; ++r) {
                sf[wnIdx][wm + ti * 16 + quad * 4 + r] = pf[r];
                sg[wnIdx][wm + ti * 16 + quad * 4 + r] = pg[r];
            }
    }
    __syncthreads();
    if (tid < 64) {
        atomicAdd(&f[m0 + tid], sf[0][tid] + sf[1][tid]);
        atomicAdd(&g[m0 + tid], sg[0][tid] + sg[1][tid]);
    }
}

__global__ __launch_bounds__(256) void rank_scatter(const float* __restrict__ g,
                                                    float* __restrict__ gs,
                                                    int* __restrict__ perm) {
    const int t = threadIdx.x;
    const int jl = t & 31;
    const int seg = t >> 5;
    const int j = blockIdx.x * 32 + jl;
    const float gj = g[j];
    const int base = seg * (NROWS / 8);
    int cnt = 0;
    for (int r = 0; r < NROWS / 8; r += 4) {
        const float4 v = *(const float4*)&g[base + r];
        const int i0 = base + r;
        cnt += (v.x < gj) || (v.x == gj && (i0 + 0) < j);
        cnt += (v.y < gj) || (v.y == gj && (i0 + 1) < j);
        cnt += (v.z < gj) || (v.z == gj && (i0 + 2) < j);
        cnt += (v.w < gj) || (v.w == gj && (i0 + 3) < j);
    }
    __shared__ int part[8][32];
    part[seg][jl] = cnt;
    __syncthreads();
    if (seg == 0) {
        int rank = 0;
#pragma unroll
        for (int s = 0; s < 8; ++s) rank += part[s][jl];
        gs[rank] = gj;
        perm[rank] = j;
    }
}

__global__ __launch_bounds__(256) void scan_pass1(const f16* __restrict__ h,
                                                  const int* __restrict__ perm,
                                                  const float* __restrict__ gs,
                                                  const float* __restrict__ f,
                                                  float* __restrict__ c0,
                                                  float* __restrict__ c1,
                                                  float* __restrict__ c1s,
                                                  int* __restrict__ n0arr) {
    const int b = blockIdx.x, c = threadIdx.x;
    if (b < NCHUNK) {
        const int base = b * CHROWS;
        __shared__ int p[CHROWS];
        __shared__ float wl[CHROWS];
        if (c < CHROWS) {
            p[c] = perm[base + c];
            wl[c] = expf(gs[base + c] - gs[NROWS - 1]);
        }
        __syncthreads();
        float s0 = 0.f, s1 = 0.f;
        for (int r = 0; r < CHROWS; ++r) {
            float v = (float)h[(size_t)p[r] * FOUT + c];
            s0 += v;
            s1 += wl[r] * v;
        }
        c0[b * FOUT + c] = s0;
        c1[b * FOUT + c] = s1;
        if (c == 0) {
            float t = 0.f;
            for (int r = 0; r < CHROWS; ++r) t += wl[r];
            c1s[b] = t;
        }
    } else {
        const int i = (b - NCHUNK) * 256 + c;
        const float tt = -f[i];
        int lo = 0, hi = NROWS;
        while (lo < hi) {
            int mid = (lo + hi) >> 1;
            if (gs[mid] <= tt) lo = mid + 1; else hi = mid;
        }
        n0arr[i] = lo;
    }
}

__global__ __launch_bounds__(256) void scan_pass2(const float* __restrict__ c0,
                                                  const float* __restrict__ c1,
                                                  const float* __restrict__ c1s,
                                                  float* __restrict__ o0,
                                                  float* __restrict__ o1,
                                                  float* __restrict__ o1s) {
    const int b = blockIdx.x, t = threadIdx.x;
    __shared__ float sb[256];
    if (b < 256) {
        const float e0 = c0[(2 * t) * FOUT + b];
        const float e1 = c0[(2 * t + 1) * FOUT + b];
        const float local = e0 + e1;
        sb[t] = local;
        __syncthreads();
        for (int off = 1; off < 256; off <<= 1) {
            float add = (t >= off) ? sb[t - off] : 0.f;
            __syncthreads();
            sb[t] += add;
            __syncthreads();
        }
        const float ex = sb[t] - local;
        o0[(2 * t) * FOUT + b] = ex;
        o0[(2 * t + 1) * FOUT + b] = ex + e0;
    } else if (b < 512) {
        const int col = b - 256;
        const float e0 = c1[(2 * t) * FOUT + col];
        const float e1 = c1[(2 * t + 1) * FOUT + col];
        const float local = e0 + e1;
        sb[t] = local;
        __syncthreads();
        for (int off = 1; off < 256; off <<= 1) {
            float add = (t + off < 256) ? sb[t + off] : 0.f;
            __syncthreads();
            sb[t] += add;
            __syncthreads();
        }
        const float exs = sb[t] - local;
        o1[(2 * t) * FOUT + col] = exs + e1;
        o1[(2 * t + 1) * FOUT + col] = exs;
    } else {
        const float e0 = c1s[2 * t];
        const float e1 = c1s[2 * t + 1];
        const float local = e0 + e1;
        sb[t] = local;
        __syncthreads();
        for (int off = 1; off < 256; off <<= 1) {
            float add = (t + off < 256) ? sb[t + off] : 0.f;
            __syncthreads();
            sb[t] += add;
            __syncthreads();
        }
        const float exs = sb[t] - local;
        o1s[2 * t] = exs + e1;
        o1s[2 * t + 1] = exs;
    }
}

__global__ __launch_bounds__(256) void scan_pass3(const f16* __restrict__ h,
                                                  const int* __restrict__ perm,
                                                  const float* __restrict__ gs,
                                                  const float* __restrict__ o0,
                                                  const float* __restrict__ o1,
                                                  const float* __restrict__ o1s,
                                                  f16* __restrict__ P0,
                                                  f16* __restrict__ S1,
                                                  float* __restrict__ S1s) {
    const int k = blockIdx.x, c = threadIdx.x;
    const int base = k * CHROWS;
    __shared__ int p[CHROWS];
    __shared__ float wl[CHROWS];
    if (c < CHROWS) {
        p[c] = perm[base + c];
        wl[c] = expf(gs[base + c] - gs[NROWS - 1]);
    }
    __syncthreads();
    float run0 = o0[k * FOUT + c];
    for (int r = 0; r < CHROWS; ++r) {
        P0[(size_t)(base + r) * FOUT + c] = (f16)run0;
        run0 += (float)h[(size_t)p[r] * FOUT + c];
    }
    float run1 = o1[k * FOUT + c];
    for (int r = CHROWS - 1; r >= 0; --r) {
        run1 += wl[r] * (float)h[(size_t)p[r] * FOUT + c];
        S1[(size_t)(base + r) * FOUT + c] = (f16)run1;
    }
    if (c == 0) {
        float rs = o1s[k];
        for (int r = CHROWS - 1; r >= 0; --r) { rs += wl[r]; S1s[base + r] = rs; }
    }
    if (k == NCHUNK - 1) {
        P0[(size_t)NROWS * FOUT + c] = (f16)run0;
        S1[(size_t)NROWS * FOUT + c] = (f16)0.f;
        if (c == 0) S1s[NROWS] = 0.f;
    }
}

__global__ __launch_bounds__(256) void final_kernel(const float* __restrict__ f,
                                                    const float* __restrict__ gs,
                                                    const int* __restrict__ n0arr,
                                                    const f16* __restrict__ P0,
                                                    const f16* __restrict__ S1,
                                                    const float* __restrict__ S1s,
                                                    float* __restrict__ out) {
    const int b = blockIdx.x, c = threadIdx.x;
    const float gm = gs[NROWS - 1];
#pragma unroll
    for (int rr = 0; rr < 4; ++rr) {
        const int i = b * 4 + rr;
        const float fi = f[i];
        const int n0 = n0arr[i];
        const float m = fmaxf(0.f, fi + gm);
        const float A = expf(-m);
        const float B = expf(fi + gm - m);
        const float denom = A * (float)n0 + B * S1s[n0];
        const float numer = A * (float)P0[(size_t)n0 * FOUT + c]
                          + B * (float)S1[(size_t)n0 * FOUT + c];
        const float v = numer / denom;
        out[(size_t)i * FOUT + c] = v > 0.f ? v : expm1f(v);
    }
}

extern "C" void kernel_launch(void* const* d_in, const int* in_sizes, int n_in,
                              void* d_out, int out_size, void* d_ws, size_t ws_size,
                              hipStream_t stream) {
    (void)in_sizes; (void)n_in; (void)out_size; (void)ws_size;
    const float* x = (const float*)d_in[0];
    const float* W = (const float*)d_in[1];
    const float* a = (const float*)d_in[2];
    float* out = (float*)d_out;
    char* ws = (char*)d_ws;

    void* args[] = { (void*)&x, (void*)&W, (void*)&a, (void*)&out, (void*)&ws };
    hipError_t err = hipLaunchCooperativeKernel((const void*)mega, dim3(512), dim3(256),
                                                args, 0, stream);
    if (err == hipSuccess) return;

    // ---- fallback: proven 7-kernel pipeline ----
    f16*   xh   = (f16*)(ws + OFF_XH);
    f16*   Wt   = (f16*)(ws + OFF_WT);
    f16*   h    = (f16*)(ws + OFF_H);
    f16*   P0   = (f16*)(ws + OFF_P0);
    f16*   S1   = (f16*)(ws + OFF_S1);
    float* fg   = (float*)(ws + OFF_FG);
    float* f    = fg;
    float* g    = fg + NROWS;
    float* gs   = (float*)(ws + OFF_GS);
    int*   perm = (int*)(ws + OFF_PERM);
    int*   n0arr= (int*)(ws + OFF_N0);
    float* c0   = (float*)(ws + OFF_C0);
    float* c1   = (float*)(ws + OFF_C1);
    float* o0   = (float*)(ws + OFF_O0);
    float* o1   = (float*)(ws + OFF_O1);
    float* c1s  = (float*)(ws + OFF_C1S);
    float* o1s  = (float*)(ws + OFF_O1S);
    float* S1s  = (float*)(ws + OFF_S1S);

    prep<<<512, 256, 0, stream>>>(x, W, xh, Wt, fg);
    gemm_fg<<<dim3(FOUT / 64, NROWS / 64), 256, 0, stream>>>(xh, Wt, a, h, f, g);
    rank_scatter<<<NROWS / 32, 256, 0, stream>>>(g, gs, perm);
    scan_pass1<<<NCHUNK + 32, 256, 0, stream>>>(h, perm, gs, f, c0, c1, c1s, n0arr);
    scan_pass2<<<513, 256, 0, stream>>>(c0, c1, c1s, o0, o1, o1s);
    scan_pass3<<<NCHUNK, 256, 0, stream>>>(h, perm, gs, o0, o1, o1s, P0, S1, S1s);
    final_kernel<<<NROWS / 4, 256, 0, stream>>>(f, gs, n0arr, P0, S1, S1s, out);
}

// Round 2
// 401.440 us; speedup vs baseline: 1.8270x; 1.8270x over previous
//
#include <hip/hip_runtime.h>
#include <math.h>

#define NROWS 8192
#define FIN   512
#define FOUT  256
#define NCHUNK 512
#define CHROWS 16   // NROWS / NCHUNK
#define NB    512   // grid size of mega

typedef _Float16 f16;
typedef _Float16 f16x8 __attribute__((ext_vector_type(8)));
typedef float    f32x4 __attribute__((ext_vector_type(4)));

// ---------------- workspace layout ----------------
constexpr size_t AL(size_t v) { return (v + 255) & ~(size_t)255; }
constexpr size_t SZ_XH  = (size_t)NROWS * FIN * 2;
constexpr size_t SZ_WT  = (size_t)FOUT * FIN * 2;
constexpr size_t SZ_H   = (size_t)NROWS * FOUT * 2;
constexpr size_t SZ_PS  = (size_t)(NROWS + 1) * FOUT * 2;
constexpr size_t SZ_FG  = (size_t)2 * NROWS * 4;
constexpr size_t SZ_I   = (size_t)NROWS * 4;
constexpr size_t SZ_C   = (size_t)NCHUNK * FOUT * 4;
constexpr size_t SZ_CS  = (size_t)NCHUNK * 4;
constexpr size_t SZ_S1S = (size_t)(NROWS + 1) * 4;

constexpr size_t OFF_XH   = 0;
constexpr size_t OFF_WT   = OFF_XH   + AL(SZ_XH);
constexpr size_t OFF_H    = OFF_WT   + AL(SZ_WT);
constexpr size_t OFF_P0   = OFF_H    + AL(SZ_H);
constexpr size_t OFF_S1   = OFF_P0   + AL(SZ_PS);
constexpr size_t OFF_FG   = OFF_S1   + AL(SZ_PS);
constexpr size_t OFF_GS   = OFF_FG   + AL(SZ_FG);
constexpr size_t OFF_PERM = OFF_GS   + AL(SZ_I);
constexpr size_t OFF_N0   = OFF_PERM + AL(SZ_I);
constexpr size_t OFF_C0   = OFF_N0   + AL(SZ_I);
constexpr size_t OFF_C1   = OFF_C0   + AL(SZ_C);
constexpr size_t OFF_O0   = OFF_C1   + AL(SZ_C);
constexpr size_t OFF_O1   = OFF_O0   + AL(SZ_C);
constexpr size_t OFF_C1S  = OFF_O1   + AL(SZ_C);
constexpr size_t OFF_O1S  = OFF_C1S  + AL(SZ_CS);
constexpr size_t OFF_S1S  = OFF_O1S  + AL(SZ_CS);
constexpr size_t OFF_CNT  = OFF_S1S  + AL(SZ_S1S);

// ---------------- LDS union (max 35,840 B) ----------------
union SmemU {
    struct { f16 As[64][136]; f16 Bs[64][136]; float sf[2][64], sg[2][64]; } g;
    struct { int part[16][16]; } r;
    struct { int p[CHROWS]; float wl[CHROWS]; } c;
    struct { float sb[256]; } s;
};

// ---------------- lightweight grid barrier ----------------
// Monotonic counter: no reset race. Agent-scope RMW release-chain +
// acquire spin gives cross-XCD visibility (L2 wb/inv emitted by scope).
// Capacity proof for raw launch: LDS 35840*4<=160K, 4 waves*8<=32,
// VGPR ~56 -> >=4 blocks/CU * 256 CU >= 1024 slots > 512 blocks, so the
// whole grid is resident and the spin cannot deadlock.
__device__ __forceinline__ void gridbar(unsigned* cnt, unsigned target) {
    __syncthreads();
    if (threadIdx.x == 0) {
        __hip_atomic_fetch_add(cnt, 1u, __ATOMIC_ACQ_REL, __HIP_MEMORY_SCOPE_AGENT);
        while (__hip_atomic_load(cnt, __ATOMIC_ACQUIRE, __HIP_MEMORY_SCOPE_AGENT) < target) {
        }
    }
    __syncthreads();
}

// =======================================================================
// MEGA: whole pipeline, one raw launch, 6 custom barriers
// =======================================================================
__global__ __launch_bounds__(256, 2) void mega(const float* __restrict__ x,
                                               const float* __restrict__ W,
                                               const float* __restrict__ a,
                                               float* __restrict__ out,
                                               char* __restrict__ ws) {
    __shared__ SmemU sm;
    const int b = blockIdx.x, tid = threadIdx.x;

    f16*   xh   = (f16*)(ws + OFF_XH);
    f16*   Wt   = (f16*)(ws + OFF_WT);
    f16*   hb   = (f16*)(ws + OFF_H);
    f16*   P0b  = (f16*)(ws + OFF_P0);
    f16*   S1b  = (f16*)(ws + OFF_S1);
    float* fArr = (float*)(ws + OFF_FG);
    float* gArr = fArr + NROWS;
    float* gs   = (float*)(ws + OFF_GS);
    int*   perm = (int*)(ws + OFF_PERM);
    int*   n0arr= (int*)(ws + OFF_N0);
    float* c0   = (float*)(ws + OFF_C0);
    float* c1   = (float*)(ws + OFF_C1);
    float* o0   = (float*)(ws + OFF_O0);
    float* o1   = (float*)(ws + OFF_O1);
    float* c1s  = (float*)(ws + OFF_C1S);
    float* o1s  = (float*)(ws + OFF_O1S);
    float* S1s  = (float*)(ws + OFF_S1S);
    unsigned* cnt = (unsigned*)(ws + OFF_CNT);

    // ---- P0: prep (x->f16; W->Wt transposed f16; zero f/g) ----
    if (b < 256) {
        const size_t base = (size_t)b * 16384;
#pragma unroll 4
        for (int i = 0; i < 16; ++i) {
            const size_t idx = base + (size_t)i * 1024 + tid * 4;
            float4 v = *(const float4*)&x[idx];
            union { f16 h4[4]; ushort4 u; } cv;
            cv.h4[0] = (f16)v.x; cv.h4[1] = (f16)v.y;
            cv.h4[2] = (f16)v.z; cv.h4[3] = (f16)v.w;
            *(ushort4*)&xh[idx] = cv.u;
        }
    } else {
        const int n = b - 256;
        Wt[(size_t)n * FIN + tid]       = (f16)W[(size_t)tid * FOUT + n];
        Wt[(size_t)n * FIN + tid + 256] = (f16)W[(size_t)(tid + 256) * FOUT + n];
        if (n < 64) fArr[n * 256 + tid] = 0.f;   // zeros both f and g
    }
    gridbar(cnt, 1 * NB);

    // ---- P1: GEMM h = x@W (f16 MFMA, BK=128) + f/g partials ----
    {
        const int n0 = (b & 3) * 64;
        const int m0 = (b >> 2) * 64;
        const int srow = tid >> 2, sseg = (tid & 3) * 8;
        const int w = tid >> 6, lane = tid & 63;
        const int wm = (w & 1) * 32, wn = (w >> 1) * 32;
        const int l15 = lane & 15, quad = lane >> 4;

        f16x8 pa[4], pb[4];
#pragma unroll
        for (int j = 0; j < 4; ++j) {
            pa[j] = *(const f16x8*)&xh[(size_t)(m0 + srow) * FIN + j * 32 + sseg];
            pb[j] = *(const f16x8*)&Wt[(size_t)(n0 + srow) * FIN + j * 32 + sseg];
        }

        f32x4 acc[2][2] = {};
        for (int k0 = 0; k0 < FIN; k0 += 128) {
            __syncthreads();
#pragma unroll
            for (int j = 0; j < 4; ++j) {
                *(f16x8*)&sm.g.As[srow][j * 32 + sseg] = pa[j];
                *(f16x8*)&sm.g.Bs[srow][j * 32 + sseg] = pb[j];
            }
            __syncthreads();
            if (k0 + 128 < FIN) {
#pragma unroll
                for (int j = 0; j < 4; ++j) {
                    pa[j] = *(const f16x8*)&xh[(size_t)(m0 + srow) * FIN + k0 + 128 + j * 32 + sseg];
                    pb[j] = *(const f16x8*)&Wt[(size_t)(n0 + srow) * FIN + k0 + 128 + j * 32 + sseg];
                }
            }
#pragma unroll
            for (int kk = 0; kk < 4; ++kk) {
                f16x8 af[2], bf[2];
#pragma unroll
                for (int ti = 0; ti < 2; ++ti)
                    af[ti] = *(const f16x8*)&sm.g.As[wm + ti * 16 + l15][kk * 32 + quad * 8];
#pragma unroll
                for (int tj = 0; tj < 2; ++tj)
                    bf[tj] = *(const f16x8*)&sm.g.Bs[wn + tj * 16 + l15][kk * 32 + quad * 8];
#pragma unroll
                for (int ti = 0; ti < 2; ++ti)
#pragma unroll
                    for (int tj = 0; tj < 2; ++tj)
                        acc[ti][tj] = __builtin_amdgcn_mfma_f32_16x16x32_f16(af[ti], bf[tj], acc[ti][tj], 0, 0, 0);
            }
        }
#pragma unroll
        for (int ti = 0; ti < 2; ++ti)
#pragma unroll
            for (int tj = 0; tj < 2; ++tj) {
                const int col = n0 + wn + tj * 16 + l15;
#pragma unroll
                for (int r = 0; r < 4; ++r) {
                    const int row = m0 + wm + ti * 16 + quad * 4 + r;
                    hb[(size_t)row * FOUT + col] = (f16)acc[ti][tj][r];
                }
            }
        const float a1c0 = a[n0 + wn + l15];
        const float a1c1 = a[n0 + wn + 16 + l15];
        const float a2c0 = a[FOUT + n0 + wn + l15];
        const float a2c1 = a[FOUT + n0 + wn + 16 + l15];
        const int wnIdx = w >> 1;
#pragma unroll
        for (int ti = 0; ti < 2; ++ti) {
            float pf[4], pg[4];
#pragma unroll
            for (int r = 0; r < 4; ++r) {
                pf[r] = acc[ti][0][r] * a1c0 + acc[ti][1][r] * a1c1;
                pg[r] = acc[ti][0][r] * a2c0 + acc[ti][1][r] * a2c1;
            }
#pragma unroll
            for (int off = 8; off >= 1; off >>= 1)
#pragma unroll
                for (int r = 0; r < 4; ++r) {
                    pf[r] += __shfl_xor(pf[r], off, 16);
                    pg[r] += __shfl_xor(pg[r], off, 16);
                }
            if (l15 == 0)
#pragma unroll
                for (int r = 0; r < 4; ++r) {
                    sm.g.sf[wnIdx][wm + ti * 16 + quad * 4 + r] = pf[r];
                    sm.g.sg[wnIdx][wm + ti * 16 + quad * 4 + r] = pg[r];
                }
        }
        __syncthreads();
        if (tid < 64) {
            atomicAdd(&fArr[m0 + tid], sm.g.sf[0][tid] + sm.g.sf[1][tid]);
            atomicAdd(&gArr[m0 + tid], sm.g.sg[0][tid] + sm.g.sg[1][tid]);
        }
    }
    gridbar(cnt, 2 * NB);

    // ---- P2: rank + scatter (512 blocks x 16 j, 16 segments of 512) ----
    {
        const int jl = tid & 15, seg = tid >> 4;
        const int j = b * 16 + jl;
        const float gj = gArr[j];
        const int base = seg * 512;
        int cntj = 0;
#pragma unroll 4
        for (int r = 0; r < 512; r += 4) {
            const float4 v = *(const float4*)&gArr[base + r];
            const int i0 = base + r;
            cntj += (v.x < gj) || (v.x == gj && (i0 + 0) < j);
            cntj += (v.y < gj) || (v.y == gj && (i0 + 1) < j);
            cntj += (v.z < gj) || (v.z == gj && (i0 + 2) < j);
            cntj += (v.w < gj) || (v.w == gj && (i0 + 3) < j);
        }
        sm.r.part[seg][jl] = cntj;
        __syncthreads();
        if (seg == 0) {
            int rank = 0;
#pragma unroll
            for (int ss = 0; ss < 16; ++ss) rank += sm.r.part[ss][jl];
            gs[rank] = gj;
            perm[rank] = j;
        }
    }
    gridbar(cnt, 3 * NB);

    // ---- P3: per-chunk sums (c0, c1, c1s) ----
    {
        const int base = b * CHROWS;
        if (tid < CHROWS) {
            sm.c.p[tid] = perm[base + tid];
            sm.c.wl[tid] = expf(gs[base + tid] - gs[NROWS - 1]);
        }
        __syncthreads();
        float s0 = 0.f, s1v = 0.f;
        for (int r = 0; r < CHROWS; ++r) {
            float v = (float)hb[(size_t)sm.c.p[r] * FOUT + tid];
            s0 += v;
            s1v += sm.c.wl[r] * v;
        }
        c0[b * FOUT + tid] = s0;
        c1[b * FOUT + tid] = s1v;
        if (tid == 0) {
            float t2 = 0.f;
            for (int r = 0; r < CHROWS; ++r) t2 += sm.c.wl[r];
            c1s[b] = t2;
        }
    }
    gridbar(cnt, 4 * NB);

    // ---- P4: column scans (blocks 0-255) + n0 searches (256-287) ----
    if (b < 256) {
        const int col = b;
        {   // exclusive prefix over c0 column
            const float e0 = c0[(2 * tid) * FOUT + col];
            const float e1 = c0[(2 * tid + 1) * FOUT + col];
            const float local = e0 + e1;
            sm.s.sb[tid] = local;
            __syncthreads();
            for (int off = 1; off < 256; off <<= 1) {
                float add = (tid >= off) ? sm.s.sb[tid - off] : 0.f;
                __syncthreads();
                sm.s.sb[tid] += add;
                __syncthreads();
            }
            const float ex = sm.s.sb[tid] - local;
            o0[(2 * tid) * FOUT + col] = ex;
            o0[(2 * tid + 1) * FOUT + col] = ex + e0;
        }
        __syncthreads();
        {   // exclusive suffix over c1 column
            const float e0 = c1[(2 * tid) * FOUT + col];
            const float e1 = c1[(2 * tid + 1) * FOUT + col];
            const float local = e0 + e1;
            sm.s.sb[tid] = local;
            __syncthreads();
            for (int off = 1; off < 256; off <<= 1) {
                float add = (tid + off < 256) ? sm.s.sb[tid + off] : 0.f;
                __syncthreads();
                sm.s.sb[tid] += add;
                __syncthreads();
            }
            const float exs = sm.s.sb[tid] - local;
            o1[(2 * tid) * FOUT + col] = exs + e1;
            o1[(2 * tid + 1) * FOUT + col] = exs;
        }
        if (b == 0) {   // exclusive suffix over c1s (scalar)
            __syncthreads();
            const float e0 = c1s[2 * tid];
            const float e1 = c1s[2 * tid + 1];
            const float local = e0 + e1;
            sm.s.sb[tid] = local;
            __syncthreads();
            for (int off = 1; off < 256; off <<= 1) {
                float add = (tid + off < 256) ? sm.s.sb[tid + off] : 0.f;
                __syncthreads();
                sm.s.sb[tid] += add;
                __syncthreads();
            }
            const float exs = sm.s.sb[tid] - local;
            o1s[2 * tid] = exs + e1;
            o1s[2 * tid + 1] = exs;
        }
    } else if (b < 288) {
        const int i = (b - 256) * 256 + tid;   // 0..8191
        const float tt = -fArr[i];
        int lo = 0, hi = NROWS;
        while (lo < hi) {
            int mid = (lo + hi) >> 1;
            if (gs[mid] <= tt) lo = mid + 1; else hi = mid;
        }
        n0arr[i] = lo;
    }
    gridbar(cnt, 5 * NB);

    // ---- P5: element-granular P0 / S1 / S1s ----
    {
        const int base = b * CHROWS;
        if (tid < CHROWS) {
            sm.c.p[tid] = perm[base + tid];
            sm.c.wl[tid] = expf(gs[base + tid] - gs[NROWS - 1]);
        }
        __syncthreads();
        float run0 = o0[b * FOUT + tid];
        for (int r = 0; r < CHROWS; ++r) {
            P0b[(size_t)(base + r) * FOUT + tid] = (f16)run0;
            run0 += (float)hb[(size_t)sm.c.p[r] * FOUT + tid];
        }
        float run1 = o1[b * FOUT + tid];
        for (int r = CHROWS - 1; r >= 0; --r) {
            run1 += sm.c.wl[r] * (float)hb[(size_t)sm.c.p[r] * FOUT + tid];
            S1b[(size_t)(base + r) * FOUT + tid] = (f16)run1;
        }
        if (tid == 0) {
            float rs = o1s[b];
            for (int r = CHROWS - 1; r >= 0; --r) { rs += sm.c.wl[r]; S1s[base + r] = rs; }
        }
        if (b == NCHUNK - 1) {
            P0b[(size_t)NROWS * FOUT + tid] = (f16)run0;
            S1b[(size_t)NROWS * FOUT + tid] = (f16)0.f;
            if (tid == 0) S1s[NROWS] = 0.f;
        }
    }
    gridbar(cnt, 6 * NB);

    // ---- P6: streaming combine + ELU (16 rows / block) ----
    {
        const float gm = gs[NROWS - 1];
#pragma unroll 4
        for (int rr = 0; rr < 16; ++rr) {
            const int i = b * 16 + rr;
            const float fi = fArr[i];
            const int n0i = n0arr[i];
            const float m = fmaxf(0.f, fi + gm);
            const float A = expf(-m);
            const float B = expf(fi + gm - m);
            const float denom = A * (float)n0i + B * S1s[n0i];
            const float numer = A * (float)P0b[(size_t)n0i * FOUT + tid]
                              + B * (float)S1b[(size_t)n0i * FOUT + tid];
            const float v = numer / denom;
            out[(size_t)i * FOUT + tid] = v > 0.f ? v : expm1f(v);
        }
    }
}

extern "C" void kernel_launch(void* const* d_in, const int* in_sizes, int n_in,
                              void* d_out, int out_size, void* d_ws, size_t ws_size,
                              hipStream_t stream) {
    (void)in_sizes; (void)n_in; (void)out_size; (void)ws_size;
    const float* x = (const float*)d_in[0];
    const float* W = (const float*)d_in[1];
    const float* a = (const float*)d_in[2];
    float* out = (float*)d_out;
    char* ws = (char*)d_ws;

    // zero the barrier counter (workspace is re-poisoned between iters)
    hipMemsetAsync(ws + OFF_CNT, 0, 256, stream);
    mega<<<NB, 256, 0, stream>>>(x, W, a, out, ws);
}

// Round 4
// 205.104 us; speedup vs baseline: 3.5759x; 1.9572x over previous
//
#include <hip/hip_runtime.h>
#include <math.h>

#define NROWS 8192
#define FIN   512
#define FOUT  256
#define NCHUNK 512
#define CHROWS 16   // NROWS / NCHUNK
#define NB    512   // grid size of mega
#define FLAG_STRIDE 16  // 16 uints = 64 B per flag line

typedef _Float16 f16;
typedef _Float16 f16x8 __attribute__((ext_vector_type(8)));
typedef float    f32x4 __attribute__((ext_vector_type(4)));

// ---------------- workspace layout ----------------
constexpr size_t AL(size_t v) { return (v + 255) & ~(size_t)255; }
constexpr size_t SZ_XH  = (size_t)NROWS * FIN * 2;
constexpr size_t SZ_WT  = (size_t)FOUT * FIN * 2;
constexpr size_t SZ_H   = (size_t)NROWS * FOUT * 2;
constexpr size_t SZ_PS  = (size_t)(NROWS + 1) * FOUT * 2;
constexpr size_t SZ_FG  = (size_t)2 * NROWS * 4;
constexpr size_t SZ_I   = (size_t)NROWS * 4;
constexpr size_t SZ_C   = (size_t)NCHUNK * FOUT * 4;
constexpr size_t SZ_CS  = (size_t)NCHUNK * 4;
constexpr size_t SZ_S1S = (size_t)(NROWS + 1) * 4;
constexpr size_t SZ_BAR = (size_t)(NB + 1) * FLAG_STRIDE * 4;  // flags + go

constexpr size_t OFF_XH   = 0;
constexpr size_t OFF_WT   = OFF_XH   + AL(SZ_XH);
constexpr size_t OFF_H    = OFF_WT   + AL(SZ_WT);
constexpr size_t OFF_P0   = OFF_H    + AL(SZ_H);
constexpr size_t OFF_S1   = OFF_P0   + AL(SZ_PS);
constexpr size_t OFF_FG   = OFF_S1   + AL(SZ_PS);
constexpr size_t OFF_GS   = OFF_FG   + AL(SZ_FG);
constexpr size_t OFF_PERM = OFF_GS   + AL(SZ_I);
constexpr size_t OFF_N0   = OFF_PERM + AL(SZ_I);
constexpr size_t OFF_C0   = OFF_N0   + AL(SZ_I);
constexpr size_t OFF_C1   = OFF_C0   + AL(SZ_C);
constexpr size_t OFF_O0   = OFF_C1   + AL(SZ_C);
constexpr size_t OFF_O1   = OFF_O0   + AL(SZ_C);
constexpr size_t OFF_C1S  = OFF_O1   + AL(SZ_C);
constexpr size_t OFF_O1S  = OFF_C1S  + AL(SZ_CS);
constexpr size_t OFF_S1S  = OFF_O1S  + AL(SZ_CS);
constexpr size_t OFF_BAR  = OFF_S1S  + AL(SZ_S1S);

// ---------------- LDS union (max 35,840 B) ----------------
union SmemU {
    struct { f16 As[64][136]; f16 Bs[64][136]; float sf[2][64], sg[2][64]; } g;
    struct { int part[16][16]; } r;
    struct { int p[CHROWS]; float wl[CHROWS]; } c;
    struct { float sb[256]; } s;
};

// ---------------- flag/master grid barrier, zero RMWs ----------------
// Arrival: per-block padded flag, release store (one L2 wb per block).
// Master (block NB-1): RELAXED polls of 512 independent lines, then one
// release store to `go`. Spin: RELAXED loads + s_sleep throttle, ONE
// acquire fence on exit (no per-poll invalidate storm).
// Residency proof: LDS 35840*4 <= 160K, 16 waves <= 32, VGPR ~56 ->
// >=4 blocks/CU * 256 CU >= 1024 slots > 512 blocks resident.
__device__ __forceinline__ void gridbar(unsigned* flags, unsigned* go,
                                        int b, unsigned k) {
    __syncthreads();
    if (threadIdx.x == 0) {
        __hip_atomic_store(&flags[(size_t)b * FLAG_STRIDE], k,
                           __ATOMIC_RELEASE, __HIP_MEMORY_SCOPE_AGENT);
    }
    if (b == NB - 1) {
        const int t = threadIdx.x;
#pragma unroll
        for (int i = 0; i < NB / 256; ++i) {
            const int idx = i * 256 + t;
            while (__hip_atomic_load(&flags[(size_t)idx * FLAG_STRIDE],
                                     __ATOMIC_RELAXED, __HIP_MEMORY_SCOPE_AGENT) < k)
                __builtin_amdgcn_s_sleep(1);
        }
        __syncthreads();
        if (t == 0)
            __hip_atomic_store(go, k, __ATOMIC_RELEASE, __HIP_MEMORY_SCOPE_AGENT);
    }
    if (threadIdx.x == 0) {
        while (__hip_atomic_load(go, __ATOMIC_RELAXED, __HIP_MEMORY_SCOPE_AGENT) < k)
            __builtin_amdgcn_s_sleep(2);
        __builtin_amdgcn_fence(__ATOMIC_ACQUIRE, "agent");
    }
    __syncthreads();
}

// =======================================================================
// MEGA: whole pipeline, one raw launch, 6 flag barriers
// =======================================================================
__global__ __launch_bounds__(256, 2) void mega(const float* __restrict__ x,
                                               const float* __restrict__ W,
                                               const float* __restrict__ a,
                                               float* __restrict__ out,
                                               char* __restrict__ ws) {
    __shared__ SmemU sm;
    const int b = blockIdx.x, tid = threadIdx.x;

    f16*   xh   = (f16*)(ws + OFF_XH);
    f16*   Wt   = (f16*)(ws + OFF_WT);
    f16*   hb   = (f16*)(ws + OFF_H);
    f16*   P0b  = (f16*)(ws + OFF_P0);
    f16*   S1b  = (f16*)(ws + OFF_S1);
    float* fArr = (float*)(ws + OFF_FG);
    float* gArr = fArr + NROWS;
    float* gs   = (float*)(ws + OFF_GS);
    int*   perm = (int*)(ws + OFF_PERM);
    int*   n0arr= (int*)(ws + OFF_N0);
    float* c0   = (float*)(ws + OFF_C0);
    float* c1   = (float*)(ws + OFF_C1);
    float* o0   = (float*)(ws + OFF_O0);
    float* o1   = (float*)(ws + OFF_O1);
    float* c1s  = (float*)(ws + OFF_C1S);
    float* o1s  = (float*)(ws + OFF_O1S);
    float* S1s  = (float*)(ws + OFF_S1S);
    unsigned* flags = (unsigned*)(ws + OFF_BAR);
    unsigned* go    = flags + (size_t)NB * FLAG_STRIDE;

    // ---- P0: prep (x->f16; W->Wt transposed f16; zero f/g) ----
    if (b < 256) {
        const size_t base = (size_t)b * 16384;
#pragma unroll 4
        for (int i = 0; i < 16; ++i) {
            const size_t idx = base + (size_t)i * 1024 + tid * 4;
            float4 v = *(const float4*)&x[idx];
            union { f16 h4[4]; ushort4 u; } cv;
            cv.h4[0] = (f16)v.x; cv.h4[1] = (f16)v.y;
            cv.h4[2] = (f16)v.z; cv.h4[3] = (f16)v.w;
            *(ushort4*)&xh[idx] = cv.u;
        }
    } else {
        const int n = b - 256;
        Wt[(size_t)n * FIN + tid]       = (f16)W[(size_t)tid * FOUT + n];
        Wt[(size_t)n * FIN + tid + 256] = (f16)W[(size_t)(tid + 256) * FOUT + n];
        if (n < 64) fArr[n * 256 + tid] = 0.f;   // zeros both f and g
    }
    gridbar(flags, go, b, 1);

    // ---- P1: GEMM h = x@W (f16 MFMA, BK=128) + f/g partials ----
    {
        const int n0 = (b & 3) * 64;
        const int m0 = (b >> 2) * 64;
        const int srow = tid >> 2, sseg = (tid & 3) * 8;
        const int w = tid >> 6, lane = tid & 63;
        const int wm = (w & 1) * 32, wn = (w >> 1) * 32;
        const int l15 = lane & 15, quad = lane >> 4;

        f16x8 pa[4], pb[4];
#pragma unroll
        for (int j = 0; j < 4; ++j) {
            pa[j] = *(const f16x8*)&xh[(size_t)(m0 + srow) * FIN + j * 32 + sseg];
            pb[j] = *(const f16x8*)&Wt[(size_t)(n0 + srow) * FIN + j * 32 + sseg];
        }

        f32x4 acc[2][2] = {};
        for (int k0 = 0; k0 < FIN; k0 += 128) {
            __syncthreads();
#pragma unroll
            for (int j = 0; j < 4; ++j) {
                *(f16x8*)&sm.g.As[srow][j * 32 + sseg] = pa[j];
                *(f16x8*)&sm.g.Bs[srow][j * 32 + sseg] = pb[j];
            }
            __syncthreads();
            if (k0 + 128 < FIN) {
#pragma unroll
                for (int j = 0; j < 4; ++j) {
                    pa[j] = *(const f16x8*)&xh[(size_t)(m0 + srow) * FIN + k0 + 128 + j * 32 + sseg];
                    pb[j] = *(const f16x8*)&Wt[(size_t)(n0 + srow) * FIN + k0 + 128 + j * 32 + sseg];
                }
            }
#pragma unroll
            for (int kk = 0; kk < 4; ++kk) {
                f16x8 af[2], bf[2];
#pragma unroll
                for (int ti = 0; ti < 2; ++ti)
                    af[ti] = *(const f16x8*)&sm.g.As[wm + ti * 16 + l15][kk * 32 + quad * 8];
#pragma unroll
                for (int tj = 0; tj < 2; ++tj)
                    bf[tj] = *(const f16x8*)&sm.g.Bs[wn + tj * 16 + l15][kk * 32 + quad * 8];
#pragma unroll
                for (int ti = 0; ti < 2; ++ti)
#pragma unroll
                    for (int tj = 0; tj < 2; ++tj)
                        acc[ti][tj] = __builtin_amdgcn_mfma_f32_16x16x32_f16(af[ti], bf[tj], acc[ti][tj], 0, 0, 0);
            }
        }
#pragma unroll
        for (int ti = 0; ti < 2; ++ti)
#pragma unroll
            for (int tj = 0; tj < 2; ++tj) {
                const int col = n0 + wn + tj * 16 + l15;
#pragma unroll
                for (int r = 0; r < 4; ++r) {
                    const int row = m0 + wm + ti * 16 + quad * 4 + r;
                    hb[(size_t)row * FOUT + col] = (f16)acc[ti][tj][r];
                }
            }
        const float a1c0 = a[n0 + wn + l15];
        const float a1c1 = a[n0 + wn + 16 + l15];
        const float a2c0 = a[FOUT + n0 + wn + l15];
        const float a2c1 = a[FOUT + n0 + wn + 16 + l15];
        const int wnIdx = w >> 1;
#pragma unroll
        for (int ti = 0; ti < 2; ++ti) {
            float pf[4], pg[4];
#pragma unroll
            for (int r = 0; r < 4; ++r) {
                pf[r] = acc[ti][0][r] * a1c0 + acc[ti][1][r] * a1c1;
                pg[r] = acc[ti][0][r] * a2c0 + acc[ti][1][r] * a2c1;
            }
#pragma unroll
            for (int off = 8; off >= 1; off >>= 1)
#pragma unroll
                for (int r = 0; r < 4; ++r) {
                    pf[r] += __shfl_xor(pf[r], off, 16);
                    pg[r] += __shfl_xor(pg[r], off, 16);
                }
            if (l15 == 0)
#pragma unroll
                for (int r = 0; r < 4; ++r) {
                    sm.g.sf[wnIdx][wm + ti * 16 + quad * 4 + r] = pf[r];
                    sm.g.sg[wnIdx][wm + ti * 16 + quad * 4 + r] = pg[r];
                }
        }
        __syncthreads();
        if (tid < 64) {
            atomicAdd(&fArr[m0 + tid], sm.g.sf[0][tid] + sm.g.sf[1][tid]);
            atomicAdd(&gArr[m0 + tid], sm.g.sg[0][tid] + sm.g.sg[1][tid]);
        }
    }
    gridbar(flags, go, b, 2);

    // ---- P2: rank + scatter (512 blocks x 16 j, 16 segments of 512) ----
    {
        const int jl = tid & 15, seg = tid >> 4;
        const int j = b * 16 + jl;
        const float gj = gArr[j];
        const int base = seg * 512;
        int cntj = 0;
#pragma unroll 4
        for (int r = 0; r < 512; r += 4) {
            const float4 v = *(const float4*)&gArr[base + r];
            const int i0 = base + r;
            cntj += (v.x < gj) || (v.x == gj && (i0 + 0) < j);
            cntj += (v.y < gj) || (v.y == gj && (i0 + 1) < j);
            cntj += (v.z < gj) || (v.z == gj && (i0 + 2) < j);
            cntj += (v.w < gj) || (v.w == gj && (i0 + 3) < j);
        }
        sm.r.part[seg][jl] = cntj;
        __syncthreads();
        if (seg == 0) {
            int rank = 0;
#pragma unroll
            for (int ss = 0; ss < 16; ++ss) rank += sm.r.part[ss][jl];
            gs[rank] = gj;
            perm[rank] = j;
        }
    }
    gridbar(flags, go, b, 3);

    // ---- P3: per-chunk sums (c0, c1, c1s) ----
    {
        const int base = b * CHROWS;
        if (tid < CHROWS) {
            sm.c.p[tid] = perm[base + tid];
            sm.c.wl[tid] = expf(gs[base + tid] - gs[NROWS - 1]);
        }
        __syncthreads();
        float s0 = 0.f, s1v = 0.f;
        for (int r = 0; r < CHROWS; ++r) {
            float v = (float)hb[(size_t)sm.c.p[r] * FOUT + tid];
            s0 += v;
            s1v += sm.c.wl[r] * v;
        }
        c0[b * FOUT + tid] = s0;
        c1[b * FOUT + tid] = s1v;
        if (tid == 0) {
            float t2 = 0.f;
            for (int r = 0; r < CHROWS; ++r) t2 += sm.c.wl[r];
            c1s[b] = t2;
        }
    }
    gridbar(flags, go, b, 4);

    // ---- P4: column scans (0-255) + n0 searches (256-287) + c1s scan (288) ----
    if (b < 256) {
        const int col = b;
        {   // exclusive prefix over c0 column
            const float e0 = c0[(2 * tid) * FOUT + col];
            const float e1 = c0[(2 * tid + 1) * FOUT + col];
            const float local = e0 + e1;
            sm.s.sb[tid] = local;
            __syncthreads();
            for (int off = 1; off < 256; off <<= 1) {
                float add = (tid >= off) ? sm.s.sb[tid - off] : 0.f;
                __syncthreads();
                sm.s.sb[tid] += add;
                __syncthreads();
            }
            const float ex = sm.s.sb[tid] - local;
            o0[(2 * tid) * FOUT + col] = ex;
            o0[(2 * tid + 1) * FOUT + col] = ex + e0;
        }
        __syncthreads();
        {   // exclusive suffix over c1 column
            const float e0 = c1[(2 * tid) * FOUT + col];
            const float e1 = c1[(2 * tid + 1) * FOUT + col];
            const float local = e0 + e1;
            sm.s.sb[tid] = local;
            __syncthreads();
            for (int off = 1; off < 256; off <<= 1) {
                float add = (tid + off < 256) ? sm.s.sb[tid + off] : 0.f;
                __syncthreads();
                sm.s.sb[tid] += add;
                __syncthreads();
            }
            const float exs = sm.s.sb[tid] - local;
            o1[(2 * tid) * FOUT + col] = exs + e1;
            o1[(2 * tid + 1) * FOUT + col] = exs;
        }
    } else if (b < 288) {
        const int i = (b - 256) * 256 + tid;   // 0..8191
        const float tt = -fArr[i];
        int lo = 0, hi = NROWS;
        while (lo < hi) {
            int mid = (lo + hi) >> 1;
            if (gs[mid] <= tt) lo = mid + 1; else hi = mid;
        }
        n0arr[i] = lo;
    } else if (b == 288) {   // exclusive suffix over c1s (moved off block 0)
        const float e0 = c1s[2 * tid];
        const float e1 = c1s[2 * tid + 1];
        const float local = e0 + e1;
        sm.s.sb[tid] = local;
        __syncthreads();
        for (int off = 1; off < 256; off <<= 1) {
            float add = (tid + off < 256) ? sm.s.sb[tid + off] : 0.f;
            __syncthreads();
            sm.s.sb[tid] += add;
            __syncthreads();
        }
        const float exs = sm.s.sb[tid] - local;
        o1s[2 * tid] = exs + e1;
        o1s[2 * tid + 1] = exs;
    }
    gridbar(flags, go, b, 5);

    // ---- P5: element-granular P0 / S1 / S1s ----
    {
        const int base = b * CHROWS;
        if (tid < CHROWS) {
            sm.c.p[tid] = perm[base + tid];
            sm.c.wl[tid] = expf(gs[base + tid] - gs[NROWS - 1]);
        }
        __syncthreads();
        float run0 = o0[b * FOUT + tid];
        for (int r = 0; r < CHROWS; ++r) {
            P0b[(size_t)(base + r) * FOUT + tid] = (f16)run0;
            run0 += (float)hb[(size_t)sm.c.p[r] * FOUT + tid];
        }
        float run1 = o1[b * FOUT + tid];
        for (int r = CHROWS - 1; r >= 0; --r) {
            run1 += sm.c.wl[r] * (float)hb[(size_t)sm.c.p[r] * FOUT + tid];
            S1b[(size_t)(base + r) * FOUT + tid] = (f16)run1;
        }
        if (tid == 0) {
            float rs = o1s[b];
            for (int r = CHROWS - 1; r >= 0; --r) { rs += sm.c.wl[r]; S1s[base + r] = rs; }
        }
        if (b == NCHUNK - 1) {
            P0b[(size_t)NROWS * FOUT + tid] = (f16)run0;
            S1b[(size_t)NROWS * FOUT + tid] = (f16)0.f;
            if (tid == 0) S1s[NROWS] = 0.f;
        }
    }
    gridbar(flags, go, b, 6);

    // ---- P6: streaming combine + ELU (16 rows / block) ----
    {
        const float gm = gs[NROWS - 1];
#pragma unroll 4
        for (int rr = 0; rr < 16; ++rr) {
            const int i = b * 16 + rr;
            const float fi = fArr[i];
            const int n0i = n0arr[i];
            const float m = fmaxf(0.f, fi + gm);
            const float A = expf(-m);
            const float B = expf(fi + gm - m);
            const float denom = A * (float)n0i + B * S1s[n0i];
            const float numer = A * (float)P0b[(size_t)n0i * FOUT + tid]
                              + B * (float)S1b[(size_t)n0i * FOUT + tid];
            const float v = numer / denom;
            out[(size_t)i * FOUT + tid] = v > 0.f ? v : expm1f(v);
        }
    }
}

extern "C" void kernel_launch(void* const* d_in, const int* in_sizes, int n_in,
                              void* d_out, int out_size, void* d_ws, size_t ws_size,
                              hipStream_t stream) {
    (void)in_sizes; (void)n_in; (void)out_size; (void)ws_size;
    const float* x = (const float*)d_in[0];
    const float* W = (const float*)d_in[1];
    const float* a = (const float*)d_in[2];
    float* out = (float*)d_out;
    char* ws = (char*)d_ws;

    // zero barrier flags + go (workspace is re-poisoned between iters)
    (void)hipMemsetAsync(ws + OFF_BAR, 0, SZ_BAR, stream);
    mega<<<NB, 256, 0, stream>>>(x, W, a, out, ws);
}

// Round 5
// 172.275 us; speedup vs baseline: 4.2573x; 1.1906x over previous
//
#include <hip/hip_runtime.h>
#include <math.h>

#define NROWS 8192
#define FIN   512
#define FOUT  256
#define NCHUNK 512
#define CHROWS 16   // NROWS / NCHUNK

typedef _Float16 f16;
typedef _Float16 f16x8 __attribute__((ext_vector_type(8)));
typedef float    f32x4 __attribute__((ext_vector_type(4)));

// ---- prep: W -> Wt f16 transposed [N][K]; zero fg. (x stays f32; GEMM
//      converts in-register — kills the 24 MB xh HBM roundtrip.) ----
__global__ __launch_bounds__(256) void prep_wt(const float* __restrict__ W,
                                               f16* __restrict__ Wt,
                                               float* __restrict__ fg) {
    const int n = blockIdx.x, t = threadIdx.x;
    Wt[(size_t)n * FIN + t]       = (f16)W[(size_t)t * FOUT + n];
    Wt[(size_t)n * FIN + t + 256] = (f16)W[(size_t)(t + 256) * FOUT + n];
    if (n < 64) fg[n * 256 + t] = 0.f;   // zero f and g
}

// ---- GEMM h = x@W via f16 MFMA, BK=128; A read as f32 + in-reg convert ----
__global__ __launch_bounds__(256) void gemm_fg(const float* __restrict__ x,
                                               const f16* __restrict__ Wt,
                                               const float* __restrict__ a,
                                               f16* __restrict__ h,
                                               float* __restrict__ f,
                                               float* __restrict__ g) {
    __shared__ __align__(16) f16 As[64][136];
    __shared__ __align__(16) f16 Bs[64][136];
    __shared__ float sf[2][64], sg[2][64];
    const int tid = threadIdx.x;
    const int n0 = blockIdx.x * 64;
    const int m0 = blockIdx.y * 64;
    const int srow = tid >> 2, sseg = (tid & 3) * 8;
    const int w = tid >> 6, lane = tid & 63;
    const int wm = (w & 1) * 32, wn = (w >> 1) * 32;
    const int l15 = lane & 15, quad = lane >> 4;

    float4 pa0[4], pa1[4];   // A prefetch kept f32 (convert at LDS-store)
    f16x8 pb[4];
#pragma unroll
    for (int j = 0; j < 4; ++j) {
        const float* xp = &x[(size_t)(m0 + srow) * FIN + j * 32 + sseg];
        pa0[j] = *(const float4*)xp;
        pa1[j] = *(const float4*)(xp + 4);
        pb[j] = *(const f16x8*)&Wt[(size_t)(n0 + srow) * FIN + j * 32 + sseg];
    }

    f32x4 acc[2][2] = {};
    for (int k0 = 0; k0 < FIN; k0 += 128) {
        __syncthreads();
#pragma unroll
        for (int j = 0; j < 4; ++j) {
            f16x8 t;
            t[0] = (f16)pa0[j].x; t[1] = (f16)pa0[j].y;
            t[2] = (f16)pa0[j].z; t[3] = (f16)pa0[j].w;
            t[4] = (f16)pa1[j].x; t[5] = (f16)pa1[j].y;
            t[6] = (f16)pa1[j].z; t[7] = (f16)pa1[j].w;
            *(f16x8*)&As[srow][j * 32 + sseg] = t;
            *(f16x8*)&Bs[srow][j * 32 + sseg] = pb[j];
        }
        __syncthreads();
        if (k0 + 128 < FIN) {
#pragma unroll
            for (int j = 0; j < 4; ++j) {
                const float* xp = &x[(size_t)(m0 + srow) * FIN + k0 + 128 + j * 32 + sseg];
                pa0[j] = *(const float4*)xp;
                pa1[j] = *(const float4*)(xp + 4);
                pb[j] = *(const f16x8*)&Wt[(size_t)(n0 + srow) * FIN + k0 + 128 + j * 32 + sseg];
            }
        }
#pragma unroll
        for (int kk = 0; kk < 4; ++kk) {
            f16x8 af[2], bf[2];
#pragma unroll
            for (int ti = 0; ti < 2; ++ti)
                af[ti] = *(const f16x8*)&As[wm + ti * 16 + l15][kk * 32 + quad * 8];
#pragma unroll
            for (int tj = 0; tj < 2; ++tj)
                bf[tj] = *(const f16x8*)&Bs[wn + tj * 16 + l15][kk * 32 + quad * 8];
#pragma unroll
            for (int ti = 0; ti < 2; ++ti)
#pragma unroll
                for (int tj = 0; tj < 2; ++tj)
                    acc[ti][tj] = __builtin_amdgcn_mfma_f32_16x16x32_f16(af[ti], bf[tj], acc[ti][tj], 0, 0, 0);
        }
    }
#pragma unroll
    for (int ti = 0; ti < 2; ++ti)
#pragma unroll
        for (int tj = 0; tj < 2; ++tj) {
            const int col = n0 + wn + tj * 16 + l15;
#pragma unroll
            for (int r = 0; r < 4; ++r) {
                const int row = m0 + wm + ti * 16 + quad * 4 + r;
                h[(size_t)row * FOUT + col] = (f16)acc[ti][tj][r];
            }
        }
    const float a1c0 = a[n0 + wn + l15];
    const float a1c1 = a[n0 + wn + 16 + l15];
    const float a2c0 = a[FOUT + n0 + wn + l15];
    const float a2c1 = a[FOUT + n0 + wn + 16 + l15];
    const int wnIdx = w >> 1;
#pragma unroll
    for (int ti = 0; ti < 2; ++ti) {
        float pf[4], pg[4];
#pragma unroll
        for (int r = 0; r < 4; ++r) {
            pf[r] = acc[ti][0][r] * a1c0 + acc[ti][1][r] * a1c1;
            pg[r] = acc[ti][0][r] * a2c0 + acc[ti][1][r] * a2c1;
        }
#pragma unroll
        for (int off = 8; off >= 1; off >>= 1)
#pragma unroll
            for (int r = 0; r < 4; ++r) {
                pf[r] += __shfl_xor(pf[r], off, 16);
                pg[r] += __shfl_xor(pg[r], off, 16);
            }
        if (l15 == 0)
#pragma unroll
            for (int r = 0; r < 4; ++r) {
                sf[wnIdx][wm + ti * 16 + quad * 4 + r] = pf[r];
                sg[wnIdx][wm + ti * 16 + quad * 4 + r] = pg[r];
            }
    }
    __syncthreads();
    if (tid < 64) {
        atomicAdd(&f[m0 + tid], sf[0][tid] + sf[1][tid]);
        atomicAdd(&g[m0 + tid], sg[0][tid] + sg[1][tid]);
    }
}

// ---- rank + scatter: rank_j = #{i: g_i<g_j || (==, i<j)} ----
__global__ __launch_bounds__(256) void rank_scatter(const float* __restrict__ g,
                                                    float* __restrict__ gs,
                                                    int* __restrict__ perm) {
    const int t = threadIdx.x;
    const int jl = t & 31;
    const int seg = t >> 5;
    const int j = blockIdx.x * 32 + jl;
    const float gj = g[j];
    const int base = seg * (NROWS / 8);
    int cnt = 0;
    for (int r = 0; r < NROWS / 8; r += 4) {
        const float4 v = *(const float4*)&g[base + r];
        const int i0 = base + r;
        cnt += (v.x < gj) || (v.x == gj && (i0 + 0) < j);
        cnt += (v.y < gj) || (v.y == gj && (i0 + 1) < j);
        cnt += (v.z < gj) || (v.z == gj && (i0 + 2) < j);
        cnt += (v.w < gj) || (v.w == gj && (i0 + 3) < j);
    }
    __shared__ int part[8][32];
    part[seg][jl] = cnt;
    __syncthreads();
    if (seg == 0) {
        int rank = 0;
#pragma unroll
        for (int s = 0; s < 8; ++s) rank += part[s][jl];
        gs[rank] = gj;
        perm[rank] = j;
    }
}

// ---- scan pass 1 (blocks 0-511): per-chunk sums; blocks 512-543: n0 searches ----
__global__ __launch_bounds__(256) void scan_pass1(const f16* __restrict__ h,
                                                  const int* __restrict__ perm,
                                                  const float* __restrict__ gs,
                                                  const float* __restrict__ f,
                                                  float* __restrict__ c0,
                                                  float* __restrict__ c1,
                                                  float* __restrict__ c1s,
                                                  int* __restrict__ n0arr) {
    const int b = blockIdx.x, c = threadIdx.x;
    if (b < NCHUNK) {
        const int base = b * CHROWS;
        __shared__ int p[CHROWS];
        __shared__ float wl[CHROWS];
        if (c < CHROWS) {
            p[c] = perm[base + c];
            wl[c] = expf(gs[base + c] - gs[NROWS - 1]);
        }
        __syncthreads();
        float s0 = 0.f, s1 = 0.f;
        for (int r = 0; r < CHROWS; ++r) {
            float v = (float)h[(size_t)p[r] * FOUT + c];
            s0 += v;
            s1 += wl[r] * v;
        }
        c0[b * FOUT + c] = s0;
        c1[b * FOUT + c] = s1;
        if (c == 0) {
            float t = 0.f;
            for (int r = 0; r < CHROWS; ++r) t += wl[r];
            c1s[b] = t;
        }
    } else {
        const int i = (b - NCHUNK) * 256 + c;   // 0..8191
        const float tt = -f[i];
        int lo = 0, hi = NROWS;
        while (lo < hi) {
            int mid = (lo + hi) >> 1;
            if (gs[mid] <= tt) lo = mid + 1; else hi = mid;
        }
        n0arr[i] = lo;
    }
}

// ---- scan pass 3 (fused w/ pass-2): each chunk-block redundantly computes
//      its own o0[k]/o1[k]/o1s[k] from the L2-resident c0/c1/c1s arrays,
//      then writes element-granular P0 / S1 (f16) / S1s ----
__global__ __launch_bounds__(256) void scan_pass3(const f16* __restrict__ h,
                                                  const int* __restrict__ perm,
                                                  const float* __restrict__ gs,
                                                  const float* __restrict__ c0,
                                                  const float* __restrict__ c1,
                                                  const float* __restrict__ c1s,
                                                  f16* __restrict__ P0,
                                                  f16* __restrict__ S1,
                                                  float* __restrict__ S1s) {
    const int k = blockIdx.x, c = threadIdx.x;
    const int base = k * CHROWS;
    __shared__ int p[CHROWS];
    __shared__ float wl[CHROWS];
    __shared__ float red[256];
    if (c < CHROWS) {
        p[c] = perm[base + c];
        wl[c] = expf(gs[base + c] - gs[NROWS - 1]);
    }
    // redundant cross-chunk scan: o0 = prefix(c0, j<k), o1 = suffix(c1, j>k)
    float s0 = 0.f, s1 = 0.f;
#pragma unroll 4
    for (int j = 0; j < NCHUNK; ++j) {
        const float v0 = c0[j * FOUT + c];
        const float v1 = c1[j * FOUT + c];
        s0 += (j < k) ? v0 : 0.f;
        s1 += (j > k) ? v1 : 0.f;
    }
    // o1s[k] = sum_{j>k} c1s[j]  (256-thread tree reduction)
    red[c] = ((c > k) ? c1s[c] : 0.f) + ((c + 256 > k) ? c1s[c + 256] : 0.f);
    __syncthreads();
    for (int off = 128; off >= 1; off >>= 1) {
        if (c < off) red[c] += red[c + off];
        __syncthreads();
    }
    const float o1sk = red[0];

    float run0 = s0;
    for (int r = 0; r < CHROWS; ++r) {
        P0[(size_t)(base + r) * FOUT + c] = (f16)run0;
        run0 += (float)h[(size_t)p[r] * FOUT + c];
    }
    float run1 = s1;
    for (int r = CHROWS - 1; r >= 0; --r) {
        run1 += wl[r] * (float)h[(size_t)p[r] * FOUT + c];
        S1[(size_t)(base + r) * FOUT + c] = (f16)run1;
    }
    if (c == 0) {
        float rs = o1sk;
        for (int r = CHROWS - 1; r >= 0; --r) { rs += wl[r]; S1s[base + r] = rs; }
    }
    if (k == NCHUNK - 1) {
        P0[(size_t)NROWS * FOUT + c] = (f16)run0;   // total column sum
        S1[(size_t)NROWS * FOUT + c] = (f16)0.f;
        if (c == 0) S1s[NROWS] = 0.f;
    }
}

// ---- final: streaming combine + ELU, 4 rows/block ----
__global__ __launch_bounds__(256) void final_kernel(const float* __restrict__ f,
                                                    const float* __restrict__ gs,
                                                    const int* __restrict__ n0arr,
                                                    const f16* __restrict__ P0,
                                                    const f16* __restrict__ S1,
                                                    const float* __restrict__ S1s,
                                                    float* __restrict__ out) {
    const int b = blockIdx.x, c = threadIdx.x;
    const float gm = gs[NROWS - 1];
#pragma unroll
    for (int rr = 0; rr < 4; ++rr) {
        const int i = b * 4 + rr;
        const float fi = f[i];
        const int n0 = n0arr[i];
        const float m = fmaxf(0.f, fi + gm);
        const float A = expf(-m);
        const float B = expf(fi + gm - m);
        const float denom = A * (float)n0 + B * S1s[n0];
        const float numer = A * (float)P0[(size_t)n0 * FOUT + c]
                          + B * (float)S1[(size_t)n0 * FOUT + c];
        const float v = numer / denom;
        out[(size_t)i * FOUT + c] = v > 0.f ? v : expm1f(v);
    }
}

extern "C" void kernel_launch(void* const* d_in, const int* in_sizes, int n_in,
                              void* d_out, int out_size, void* d_ws, size_t ws_size,
                              hipStream_t stream) {
    (void)in_sizes; (void)n_in; (void)out_size; (void)ws_size;
    const float* x = (const float*)d_in[0];
    const float* W = (const float*)d_in[1];
    const float* a = (const float*)d_in[2];
    float* out = (float*)d_out;

    char* ws = (char*)d_ws;
    size_t off = 0;
    auto alloc = [&](size_t bytes) -> void* {
        void* p = ws + off;
        off += (bytes + 255) & ~(size_t)255;
        return p;
    };
    f16*   Wt   = (f16*)alloc((size_t)FOUT * FIN * 2);
    f16*   h    = (f16*)alloc((size_t)NROWS * FOUT * 2);
    f16*   P0   = (f16*)alloc((size_t)(NROWS + 1) * FOUT * 2);
    f16*   S1   = (f16*)alloc((size_t)(NROWS + 1) * FOUT * 2);
    float* fg   = (float*)alloc(2 * NROWS * 4);
    float* f    = fg;
    float* g    = fg + NROWS;
    float* gs   = (float*)alloc(NROWS * 4);
    int*   perm = (int*)alloc(NROWS * 4);
    int*   n0arr= (int*)alloc(NROWS * 4);
    float* c0   = (float*)alloc(NCHUNK * FOUT * 4);
    float* c1   = (float*)alloc(NCHUNK * FOUT * 4);
    float* c1s  = (float*)alloc(NCHUNK * 4);
    float* S1s  = (float*)alloc((NROWS + 1) * 4);

    prep_wt<<<256, 256, 0, stream>>>(W, Wt, fg);
    gemm_fg<<<dim3(FOUT / 64, NROWS / 64), 256, 0, stream>>>(x, Wt, a, h, f, g);
    rank_scatter<<<NROWS / 32, 256, 0, stream>>>(g, gs, perm);
    scan_pass1<<<NCHUNK + 32, 256, 0, stream>>>(h, perm, gs, f, c0, c1, c1s, n0arr);
    scan_pass3<<<NCHUNK, 256, 0, stream>>>(h, perm, gs, c0, c1, c1s, P0, S1, S1s);
    final_kernel<<<NROWS / 4, 256, 0, stream>>>(f, gs, n0arr, P0, S1, S1s, out);
}

// Round 6
// 135.433 us; speedup vs baseline: 5.4154x; 1.2720x over previous
//
#include <hip/hip_runtime.h>
#include <math.h>

#define NROWS 8192
#define FIN   512
#define FOUT  256
#define NCHUNK 512
#define CHROWS 16   // NROWS / NCHUNK

typedef _Float16 f16;
typedef _Float16 f16x8 __attribute__((ext_vector_type(8)));
typedef float    f32x4 __attribute__((ext_vector_type(4)));

// ---- prep: W -> Wt f16 transposed [N][K]; zero fg. (x stays f32; GEMM
//      converts in-register — kills the 24 MB xh HBM roundtrip.) ----
__global__ __launch_bounds__(256) void prep_wt(const float* __restrict__ W,
                                               f16* __restrict__ Wt,
                                               float* __restrict__ fg) {
    const int n = blockIdx.x, t = threadIdx.x;
    Wt[(size_t)n * FIN + t]       = (f16)W[(size_t)t * FOUT + n];
    Wt[(size_t)n * FIN + t + 256] = (f16)W[(size_t)(t + 256) * FOUT + n];
    if (n < 64) fg[n * 256 + t] = 0.f;   // zero f and g
}

// ---- GEMM h = x@W via f16 MFMA, BK=128; A read as f32 + in-reg convert ----
__global__ __launch_bounds__(256) void gemm_fg(const float* __restrict__ x,
                                               const f16* __restrict__ Wt,
                                               const float* __restrict__ a,
                                               f16* __restrict__ h,
                                               float* __restrict__ f,
                                               float* __restrict__ g) {
    __shared__ __align__(16) f16 As[64][136];
    __shared__ __align__(16) f16 Bs[64][136];
    __shared__ float sf[2][64], sg[2][64];
    const int tid = threadIdx.x;
    const int n0 = blockIdx.x * 64;
    const int m0 = blockIdx.y * 64;
    const int srow = tid >> 2, sseg = (tid & 3) * 8;
    const int w = tid >> 6, lane = tid & 63;
    const int wm = (w & 1) * 32, wn = (w >> 1) * 32;
    const int l15 = lane & 15, quad = lane >> 4;

    float4 pa0[4], pa1[4];   // A prefetch kept f32 (convert at LDS-store)
    f16x8 pb[4];
#pragma unroll
    for (int j = 0; j < 4; ++j) {
        const float* xp = &x[(size_t)(m0 + srow) * FIN + j * 32 + sseg];
        pa0[j] = *(const float4*)xp;
        pa1[j] = *(const float4*)(xp + 4);
        pb[j] = *(const f16x8*)&Wt[(size_t)(n0 + srow) * FIN + j * 32 + sseg];
    }

    f32x4 acc[2][2] = {};
    for (int k0 = 0; k0 < FIN; k0 += 128) {
        __syncthreads();
#pragma unroll
        for (int j = 0; j < 4; ++j) {
            f16x8 t;
            t[0] = (f16)pa0[j].x; t[1] = (f16)pa0[j].y;
            t[2] = (f16)pa0[j].z; t[3] = (f16)pa0[j].w;
            t[4] = (f16)pa1[j].x; t[5] = (f16)pa1[j].y;
            t[6] = (f16)pa1[j].z; t[7] = (f16)pa1[j].w;
            *(f16x8*)&As[srow][j * 32 + sseg] = t;
            *(f16x8*)&Bs[srow][j * 32 + sseg] = pb[j];
        }
        __syncthreads();
        if (k0 + 128 < FIN) {
#pragma unroll
            for (int j = 0; j < 4; ++j) {
                const float* xp = &x[(size_t)(m0 + srow) * FIN + k0 + 128 + j * 32 + sseg];
                pa0[j] = *(const float4*)xp;
                pa1[j] = *(const float4*)(xp + 4);
                pb[j] = *(const f16x8*)&Wt[(size_t)(n0 + srow) * FIN + k0 + 128 + j * 32 + sseg];
            }
        }
#pragma unroll
        for (int kk = 0; kk < 4; ++kk) {
            f16x8 af[2], bf[2];
#pragma unroll
            for (int ti = 0; ti < 2; ++ti)
                af[ti] = *(const f16x8*)&As[wm + ti * 16 + l15][kk * 32 + quad * 8];
#pragma unroll
            for (int tj = 0; tj < 2; ++tj)
                bf[tj] = *(const f16x8*)&Bs[wn + tj * 16 + l15][kk * 32 + quad * 8];
#pragma unroll
            for (int ti = 0; ti < 2; ++ti)
#pragma unroll
                for (int tj = 0; tj < 2; ++tj)
                    acc[ti][tj] = __builtin_amdgcn_mfma_f32_16x16x32_f16(af[ti], bf[tj], acc[ti][tj], 0, 0, 0);
        }
    }
#pragma unroll
    for (int ti = 0; ti < 2; ++ti)
#pragma unroll
        for (int tj = 0; tj < 2; ++tj) {
            const int col = n0 + wn + tj * 16 + l15;
#pragma unroll
            for (int r = 0; r < 4; ++r) {
                const int row = m0 + wm + ti * 16 + quad * 4 + r;
                h[(size_t)row * FOUT + col] = (f16)acc[ti][tj][r];
            }
        }
    const float a1c0 = a[n0 + wn + l15];
    const float a1c1 = a[n0 + wn + 16 + l15];
    const float a2c0 = a[FOUT + n0 + wn + l15];
    const float a2c1 = a[FOUT + n0 + wn + 16 + l15];
    const int wnIdx = w >> 1;
#pragma unroll
    for (int ti = 0; ti < 2; ++ti) {
        float pf[4], pg[4];
#pragma unroll
        for (int r = 0; r < 4; ++r) {
            pf[r] = acc[ti][0][r] * a1c0 + acc[ti][1][r] * a1c1;
            pg[r] = acc[ti][0][r] * a2c0 + acc[ti][1][r] * a2c1;
        }
#pragma unroll
        for (int off = 8; off >= 1; off >>= 1)
#pragma unroll
            for (int r = 0; r < 4; ++r) {
                pf[r] += __shfl_xor(pf[r], off, 16);
                pg[r] += __shfl_xor(pg[r], off, 16);
            }
        if (l15 == 0)
#pragma unroll
            for (int r = 0; r < 4; ++r) {
                sf[wnIdx][wm + ti * 16 + quad * 4 + r] = pf[r];
                sg[wnIdx][wm + ti * 16 + quad * 4 + r] = pg[r];
            }
    }
    __syncthreads();
    if (tid < 64) {
        atomicAdd(&f[m0 + tid], sf[0][tid] + sf[1][tid]);
        atomicAdd(&g[m0 + tid], sg[0][tid] + sg[1][tid]);
    }
}

// ---- rank + scatter: rank_j = #{i: g_i<g_j || (==, i<j)} ----
__global__ __launch_bounds__(256) void rank_scatter(const float* __restrict__ g,
                                                    float* __restrict__ gs,
                                                    int* __restrict__ perm) {
    const int t = threadIdx.x;
    const int jl = t & 31;
    const int seg = t >> 5;
    const int j = blockIdx.x * 32 + jl;
    const float gj = g[j];
    const int base = seg * (NROWS / 8);
    int cnt = 0;
    for (int r = 0; r < NROWS / 8; r += 4) {
        const float4 v = *(const float4*)&g[base + r];
        const int i0 = base + r;
        cnt += (v.x < gj) || (v.x == gj && (i0 + 0) < j);
        cnt += (v.y < gj) || (v.y == gj && (i0 + 1) < j);
        cnt += (v.z < gj) || (v.z == gj && (i0 + 2) < j);
        cnt += (v.w < gj) || (v.w == gj && (i0 + 3) < j);
    }
    __shared__ int part[8][32];
    part[seg][jl] = cnt;
    __syncthreads();
    if (seg == 0) {
        int rank = 0;
#pragma unroll
        for (int s = 0; s < 8; ++s) rank += part[s][jl];
        gs[rank] = gj;
        perm[rank] = j;
    }
}

// ---- scan pass 1 (blocks 0-511): per-chunk sums; blocks 512-543: n0 searches ----
__global__ __launch_bounds__(256) void scan_pass1(const f16* __restrict__ h,
                                                  const int* __restrict__ perm,
                                                  const float* __restrict__ gs,
                                                  const float* __restrict__ f,
                                                  float* __restrict__ c0,
                                                  float* __restrict__ c1,
                                                  float* __restrict__ c1s,
                                                  int* __restrict__ n0arr) {
    const int b = blockIdx.x, c = threadIdx.x;
    if (b < NCHUNK) {
        const int base = b * CHROWS;
        __shared__ int p[CHROWS];
        __shared__ float wl[CHROWS];
        if (c < CHROWS) {
            p[c] = perm[base + c];
            wl[c] = expf(gs[base + c] - gs[NROWS - 1]);
        }
        __syncthreads();
        float s0 = 0.f, s1 = 0.f;
        for (int r = 0; r < CHROWS; ++r) {
            float v = (float)h[(size_t)p[r] * FOUT + c];
            s0 += v;
            s1 += wl[r] * v;
        }
        c0[b * FOUT + c] = s0;
        c1[b * FOUT + c] = s1;
        if (c == 0) {
            float t = 0.f;
            for (int r = 0; r < CHROWS; ++r) t += wl[r];
            c1s[b] = t;
        }
    } else {
        const int i = (b - NCHUNK) * 256 + c;   // 0..8191
        const float tt = -f[i];
        int lo = 0, hi = NROWS;
        while (lo < hi) {
            int mid = (lo + hi) >> 1;
            if (gs[mid] <= tt) lo = mid + 1; else hi = mid;
        }
        n0arr[i] = lo;
    }
}

// ---- scan pass 2: 512-length chunk scans, 2 elems/thread blocked ----
__global__ __launch_bounds__(256) void scan_pass2(const float* __restrict__ c0,
                                                  const float* __restrict__ c1,
                                                  const float* __restrict__ c1s,
                                                  float* __restrict__ o0,
                                                  float* __restrict__ o1,
                                                  float* __restrict__ o1s) {
    const int b = blockIdx.x, t = threadIdx.x;
    __shared__ float sb[256];
    if (b < 256) {
        // exclusive PREFIX over 512 chunks of column b of c0
        const float e0 = c0[(2 * t) * FOUT + b];
        const float e1 = c0[(2 * t + 1) * FOUT + b];
        const float local = e0 + e1;
        sb[t] = local;
        __syncthreads();
        for (int off = 1; off < 256; off <<= 1) {
            float add = (t >= off) ? sb[t - off] : 0.f;
            __syncthreads();
            sb[t] += add;
            __syncthreads();
        }
        const float ex = sb[t] - local;   // sum of chunks < 2t
        o0[(2 * t) * FOUT + b] = ex;
        o0[(2 * t + 1) * FOUT + b] = ex + e0;
    } else if (b < 512) {
        const int col = b - 256;
        // exclusive SUFFIX over 512 chunks of column col of c1
        const float e0 = c1[(2 * t) * FOUT + col];
        const float e1 = c1[(2 * t + 1) * FOUT + col];
        const float local = e0 + e1;
        sb[t] = local;
        __syncthreads();
        for (int off = 1; off < 256; off <<= 1) {
            float add = (t + off < 256) ? sb[t + off] : 0.f;
            __syncthreads();
            sb[t] += add;
            __syncthreads();
        }
        const float exs = sb[t] - local;  // sum of chunks > 2t+1
        o1[(2 * t) * FOUT + col] = exs + e1;
        o1[(2 * t + 1) * FOUT + col] = exs;
    } else {
        // exclusive SUFFIX over c1s (scalar)
        const float e0 = c1s[2 * t];
        const float e1 = c1s[2 * t + 1];
        const float local = e0 + e1;
        sb[t] = local;
        __syncthreads();
        for (int off = 1; off < 256; off <<= 1) {
            float add = (t + off < 256) ? sb[t + off] : 0.f;
            __syncthreads();
            sb[t] += add;
            __syncthreads();
        }
        const float exs = sb[t] - local;
        o1s[2 * t] = exs + e1;
        o1s[2 * t + 1] = exs;
    }
}

// ---- scan pass 3: element-granular P0 / S1 (stored f16) / S1s ----
__global__ __launch_bounds__(256) void scan_pass3(const f16* __restrict__ h,
                                                  const int* __restrict__ perm,
                                                  const float* __restrict__ gs,
                                                  const float* __restrict__ o0,
                                                  const float* __restrict__ o1,
                                                  const float* __restrict__ o1s,
                                                  f16* __restrict__ P0,
                                                  f16* __restrict__ S1,
                                                  float* __restrict__ S1s) {
    const int k = blockIdx.x, c = threadIdx.x;
    const int base = k * CHROWS;
    __shared__ int p[CHROWS];
    __shared__ float wl[CHROWS];
    if (c < CHROWS) {
        p[c] = perm[base + c];
        wl[c] = expf(gs[base + c] - gs[NROWS - 1]);
    }
    __syncthreads();
    float run0 = o0[k * FOUT + c];
    for (int r = 0; r < CHROWS; ++r) {
        P0[(size_t)(base + r) * FOUT + c] = (f16)run0;
        run0 += (float)h[(size_t)p[r] * FOUT + c];
    }
    float run1 = o1[k * FOUT + c];
    for (int r = CHROWS - 1; r >= 0; --r) {
        run1 += wl[r] * (float)h[(size_t)p[r] * FOUT + c];
        S1[(size_t)(base + r) * FOUT + c] = (f16)run1;
    }
    if (c == 0) {
        float rs = o1s[k];
        for (int r = CHROWS - 1; r >= 0; --r) { rs += wl[r]; S1s[base + r] = rs; }
    }
    if (k == NCHUNK - 1) {
        P0[(size_t)NROWS * FOUT + c] = (f16)run0;   // total column sum
        S1[(size_t)NROWS * FOUT + c] = (f16)0.f;
        if (c == 0) S1s[NROWS] = 0.f;
    }
}

// ---- final: streaming combine + ELU, 4 rows/block ----
__global__ __launch_bounds__(256) void final_kernel(const float* __restrict__ f,
                                                    const float* __restrict__ gs,
                                                    const int* __restrict__ n0arr,
                                                    const f16* __restrict__ P0,
                                                    const f16* __restrict__ S1,
                                                    const float* __restrict__ S1s,
                                                    float* __restrict__ out) {
    const int b = blockIdx.x, c = threadIdx.x;
    const float gm = gs[NROWS - 1];
#pragma unroll
    for (int rr = 0; rr < 4; ++rr) {
        const int i = b * 4 + rr;
        const float fi = f[i];
        const int n0 = n0arr[i];
        const float m = fmaxf(0.f, fi + gm);
        const float A = expf(-m);
        const float B = expf(fi + gm - m);
        const float denom = A * (float)n0 + B * S1s[n0];
        const float numer = A * (float)P0[(size_t)n0 * FOUT + c]
                          + B * (float)S1[(size_t)n0 * FOUT + c];
        const float v = numer / denom;
        out[(size_t)i * FOUT + c] = v > 0.f ? v : expm1f(v);
    }
}

extern "C" void kernel_launch(void* const* d_in, const int* in_sizes, int n_in,
                              void* d_out, int out_size, void* d_ws, size_t ws_size,
                              hipStream_t stream) {
    (void)in_sizes; (void)n_in; (void)out_size; (void)ws_size;
    const float* x = (const float*)d_in[0];
    const float* W = (const float*)d_in[1];
    const float* a = (const float*)d_in[2];
    float* out = (float*)d_out;

    char* ws = (char*)d_ws;
    size_t off = 0;
    auto alloc = [&](size_t bytes) -> void* {
        void* p = ws + off;
        off += (bytes + 255) & ~(size_t)255;
        return p;
    };
    f16*   Wt   = (f16*)alloc((size_t)FOUT * FIN * 2);
    f16*   h    = (f16*)alloc((size_t)NROWS * FOUT * 2);
    f16*   P0   = (f16*)alloc((size_t)(NROWS + 1) * FOUT * 2);
    f16*   S1   = (f16*)alloc((size_t)(NROWS + 1) * FOUT * 2);
    float* fg   = (float*)alloc(2 * NROWS * 4);
    float* f    = fg;
    float* g    = fg + NROWS;
    float* gs   = (float*)alloc(NROWS * 4);
    int*   perm = (int*)alloc(NROWS * 4);
    int*   n0arr= (int*)alloc(NROWS * 4);
    float* c0   = (float*)alloc(NCHUNK * FOUT * 4);
    float* c1   = (float*)alloc(NCHUNK * FOUT * 4);
    float* o0   = (float*)alloc(NCHUNK * FOUT * 4);
    float* o1   = (float*)alloc(NCHUNK * FOUT * 4);
    float* c1s  = (float*)alloc(NCHUNK * 4);
    float* o1s  = (float*)alloc(NCHUNK * 4);
    float* S1s  = (float*)alloc((NROWS + 1) * 4);

    prep_wt<<<256, 256, 0, stream>>>(W, Wt, fg);
    gemm_fg<<<dim3(FOUT / 64, NROWS / 64), 256, 0, stream>>>(x, Wt, a, h, f, g);
    rank_scatter<<<NROWS / 32, 256, 0, stream>>>(g, gs, perm);
    scan_pass1<<<NCHUNK + 32, 256, 0, stream>>>(h, perm, gs, f, c0, c1, c1s, n0arr);
    scan_pass2<<<513, 256, 0, stream>>>(c0, c1, c1s, o0, o1, o1s);
    scan_pass3<<<NCHUNK, 256, 0, stream>>>(h, perm, gs, o0, o1, o1s, P0, S1, S1s);
    final_kernel<<<NROWS / 4, 256, 0, stream>>>(f, gs, n0arr, P0, S1, S1s, out);
}

// Round 7
// 116.876 us; speedup vs baseline: 6.2753x; 1.1588x over previous
//
#include <hip/hip_runtime.h>
#include <math.h>

#define NROWS 8192
#define FIN   512
#define FOUT  256
#define NCHUNK 512
#define CHROWS 16   // NROWS / NCHUNK

typedef _Float16 f16;
typedef _Float16 f16x8 __attribute__((ext_vector_type(8)));
typedef float    f32x4 __attribute__((ext_vector_type(4)));

// ---- prep: W -> Wt f16 transposed [N][K]; zero fg ----
__global__ __launch_bounds__(256) void prep_wt(const float* __restrict__ W,
                                               f16* __restrict__ Wt,
                                               float* __restrict__ fg) {
    const int n = blockIdx.x, t = threadIdx.x;
    Wt[(size_t)n * FIN + t]       = (f16)W[(size_t)t * FOUT + n];
    Wt[(size_t)n * FIN + t + 256] = (f16)W[(size_t)(t + 256) * FOUT + n];
    if (n < 64) fg[n * 256 + t] = 0.f;   // zero f and g
}

// ---- GEMM h = x@W via f16 MFMA. BM=64, BN=128, BK=128, 512 threads.
//      A read f32 + in-reg convert; BN=128 halves A re-staging vs BN=64. ----
__global__ __launch_bounds__(512) void gemm_fg(const float* __restrict__ x,
                                               const f16* __restrict__ Wt,
                                               const float* __restrict__ a,
                                               f16* __restrict__ h,
                                               float* __restrict__ f,
                                               float* __restrict__ g) {
    __shared__ __align__(16) f16 As[64][136];
    __shared__ __align__(16) f16 Bs[128][136];
    __shared__ float sf[2][64], sg[2][64];
    const int tid = threadIdx.x;
    const int n0 = blockIdx.x * 128;   // 0 or 128
    const int m0 = blockIdx.y * 64;
    // A staging: 64 rows x 128 k / 512 thr = 16 f16 per thread
    const int arow = tid >> 3, aseg = (tid & 7) * 16;
    // B staging: 128 rows x 128 k / 512 thr = 32 f16 per thread
    const int brow = tid >> 2, bseg = (tid & 3) * 32;
    const int w = tid >> 6, lane = tid & 63;
    const int wm = (w & 3) * 16, wn = (w >> 2) * 64;   // wave: 16M x 64N
    const int l15 = lane & 15, quad = lane >> 4;

    float4 pa[4];   // 16 f32 (A prefetch, convert at LDS-store)
    f16x8 pb[4];    // 32 f16 (B prefetch)
#pragma unroll
    for (int j = 0; j < 4; ++j) {
        pa[j] = *(const float4*)&x[(size_t)(m0 + arow) * FIN + aseg + j * 4];
        pb[j] = *(const f16x8*)&Wt[(size_t)(n0 + brow) * FIN + bseg + j * 8];
    }

    f32x4 acc[4] = {};
    for (int k0 = 0; k0 < FIN; k0 += 128) {
        __syncthreads();
        {
            f16x8 t0, t1;
            t0[0] = (f16)pa[0].x; t0[1] = (f16)pa[0].y;
            t0[2] = (f16)pa[0].z; t0[3] = (f16)pa[0].w;
            t0[4] = (f16)pa[1].x; t0[5] = (f16)pa[1].y;
            t0[6] = (f16)pa[1].z; t0[7] = (f16)pa[1].w;
            t1[0] = (f16)pa[2].x; t1[1] = (f16)pa[2].y;
            t1[2] = (f16)pa[2].z; t1[3] = (f16)pa[2].w;
            t1[4] = (f16)pa[3].x; t1[5] = (f16)pa[3].y;
            t1[6] = (f16)pa[3].z; t1[7] = (f16)pa[3].w;
            *(f16x8*)&As[arow][aseg]     = t0;
            *(f16x8*)&As[arow][aseg + 8] = t1;
        }
#pragma unroll
        for (int j = 0; j < 4; ++j)
            *(f16x8*)&Bs[brow][bseg + j * 8] = pb[j];
        __syncthreads();
        if (k0 + 128 < FIN) {
#pragma unroll
            for (int j = 0; j < 4; ++j) {
                pa[j] = *(const float4*)&x[(size_t)(m0 + arow) * FIN + k0 + 128 + aseg + j * 4];
                pb[j] = *(const f16x8*)&Wt[(size_t)(n0 + brow) * FIN + k0 + 128 + bseg + j * 8];
            }
        }
#pragma unroll
        for (int kk = 0; kk < 4; ++kk) {
            const f16x8 af = *(const f16x8*)&As[wm + l15][kk * 32 + quad * 8];
            f16x8 bf[4];
#pragma unroll
            for (int tj = 0; tj < 4; ++tj)
                bf[tj] = *(const f16x8*)&Bs[wn + tj * 16 + l15][kk * 32 + quad * 8];
#pragma unroll
            for (int tj = 0; tj < 4; ++tj)
                acc[tj] = __builtin_amdgcn_mfma_f32_16x16x32_f16(af, bf[tj], acc[tj], 0, 0, 0);
        }
    }
    // h write: wave covers rows m0+wm..+15, cols n0+wn..+63
#pragma unroll
    for (int tj = 0; tj < 4; ++tj) {
        const int col = n0 + wn + tj * 16 + l15;
#pragma unroll
        for (int r = 0; r < 4; ++r) {
            const int row = m0 + wm + quad * 4 + r;
            h[(size_t)row * FOUT + col] = (f16)acc[tj][r];
        }
    }
    // f/g partials over this wave's 64 cols
    float a1c[4], a2c[4];
#pragma unroll
    for (int tj = 0; tj < 4; ++tj) {
        a1c[tj] = a[n0 + wn + tj * 16 + l15];
        a2c[tj] = a[FOUT + n0 + wn + tj * 16 + l15];
    }
    float pf[4], pg[4];
#pragma unroll
    for (int r = 0; r < 4; ++r) {
        pf[r] = acc[0][r] * a1c[0] + acc[1][r] * a1c[1]
              + acc[2][r] * a1c[2] + acc[3][r] * a1c[3];
        pg[r] = acc[0][r] * a2c[0] + acc[1][r] * a2c[1]
              + acc[2][r] * a2c[2] + acc[3][r] * a2c[3];
    }
#pragma unroll
    for (int off = 8; off >= 1; off >>= 1)
#pragma unroll
        for (int r = 0; r < 4; ++r) {
            pf[r] += __shfl_xor(pf[r], off, 16);
            pg[r] += __shfl_xor(pg[r], off, 16);
        }
    const int ng = w >> 2;   // n-group 0/1
    if (l15 == 0)
#pragma unroll
        for (int r = 0; r < 4; ++r) {
            sf[ng][wm + quad * 4 + r] = pf[r];
            sg[ng][wm + quad * 4 + r] = pg[r];
        }
    __syncthreads();
    if (tid < 64) {
        atomicAdd(&f[m0 + tid], sf[0][tid] + sf[1][tid]);
        atomicAdd(&g[m0 + tid], sg[0][tid] + sg[1][tid]);
    }
}

// ---- rank + scatter: 512 blocks x 16 j, 16 segments of 512 (proven in mega) ----
__global__ __launch_bounds__(256) void rank_scatter(const float* __restrict__ g,
                                                    float* __restrict__ gs,
                                                    int* __restrict__ perm) {
    const int t = threadIdx.x;
    const int jl = t & 15;
    const int seg = t >> 4;
    const int j = blockIdx.x * 16 + jl;
    const float gj = g[j];
    const int base = seg * 512;
    int cnt = 0;
#pragma unroll 4
    for (int r = 0; r < 512; r += 4) {
        const float4 v = *(const float4*)&g[base + r];
        const int i0 = base + r;
        cnt += (v.x < gj) || (v.x == gj && (i0 + 0) < j);
        cnt += (v.y < gj) || (v.y == gj && (i0 + 1) < j);
        cnt += (v.z < gj) || (v.z == gj && (i0 + 2) < j);
        cnt += (v.w < gj) || (v.w == gj && (i0 + 3) < j);
    }
    __shared__ int part[16][16];
    part[seg][jl] = cnt;
    __syncthreads();
    if (seg == 0) {
        int rank = 0;
#pragma unroll
        for (int ss = 0; ss < 16; ++ss) rank += part[ss][jl];
        gs[rank] = gj;
        perm[rank] = j;
    }
}

// ---- scan pass 1 (blocks 0-511): per-chunk sums; blocks 512-543: n0 searches ----
__global__ __launch_bounds__(256) void scan_pass1(const f16* __restrict__ h,
                                                  const int* __restrict__ perm,
                                                  const float* __restrict__ gs,
                                                  const float* __restrict__ f,
                                                  float* __restrict__ c0,
                                                  float* __restrict__ c1,
                                                  float* __restrict__ c1s,
                                                  int* __restrict__ n0arr) {
    const int b = blockIdx.x, c = threadIdx.x;
    if (b < NCHUNK) {
        const int base = b * CHROWS;
        __shared__ int p[CHROWS];
        __shared__ float wl[CHROWS];
        if (c < CHROWS) {
            p[c] = perm[base + c];
            wl[c] = expf(gs[base + c] - gs[NROWS - 1]);
        }
        __syncthreads();
        float s0 = 0.f, s1 = 0.f;
        for (int r = 0; r < CHROWS; ++r) {
            float v = (float)h[(size_t)p[r] * FOUT + c];
            s0 += v;
            s1 += wl[r] * v;
        }
        c0[b * FOUT + c] = s0;
        c1[b * FOUT + c] = s1;
        if (c == 0) {
            float t = 0.f;
            for (int r = 0; r < CHROWS; ++r) t += wl[r];
            c1s[b] = t;
        }
    } else {
        const int i = (b - NCHUNK) * 256 + c;   // 0..8191
        const float tt = -f[i];
        int lo = 0, hi = NROWS;
        while (lo < hi) {
            int mid = (lo + hi) >> 1;
            if (gs[mid] <= tt) lo = mid + 1; else hi = mid;
        }
        n0arr[i] = lo;
    }
}

// ---- scan pass 2: 512-length chunk scans, 2 elems/thread blocked ----
__global__ __launch_bounds__(256) void scan_pass2(const float* __restrict__ c0,
                                                  const float* __restrict__ c1,
                                                  const float* __restrict__ c1s,
                                                  float* __restrict__ o0,
                                                  float* __restrict__ o1,
                                                  float* __restrict__ o1s) {
    const int b = blockIdx.x, t = threadIdx.x;
    __shared__ float sb[256];
    if (b < 256) {
        const float e0 = c0[(2 * t) * FOUT + b];
        const float e1 = c0[(2 * t + 1) * FOUT + b];
        const float local = e0 + e1;
        sb[t] = local;
        __syncthreads();
        for (int off = 1; off < 256; off <<= 1) {
            float add = (t >= off) ? sb[t - off] : 0.f;
            __syncthreads();
            sb[t] += add;
            __syncthreads();
        }
        const float ex = sb[t] - local;
        o0[(2 * t) * FOUT + b] = ex;
        o0[(2 * t + 1) * FOUT + b] = ex + e0;
    } else if (b < 512) {
        const int col = b - 256;
        const float e0 = c1[(2 * t) * FOUT + col];
        const float e1 = c1[(2 * t + 1) * FOUT + col];
        const float local = e0 + e1;
        sb[t] = local;
        __syncthreads();
        for (int off = 1; off < 256; off <<= 1) {
            float add = (t + off < 256) ? sb[t + off] : 0.f;
            __syncthreads();
            sb[t] += add;
            __syncthreads();
        }
        const float exs = sb[t] - local;
        o1[(2 * t) * FOUT + col] = exs + e1;
        o1[(2 * t + 1) * FOUT + col] = exs;
    } else {
        const float e0 = c1s[2 * t];
        const float e1 = c1s[2 * t + 1];
        const float local = e0 + e1;
        sb[t] = local;
        __syncthreads();
        for (int off = 1; off < 256; off <<= 1) {
            float add = (t + off < 256) ? sb[t + off] : 0.f;
            __syncthreads();
            sb[t] += add;
            __syncthreads();
        }
        const float exs = sb[t] - local;
        o1s[2 * t] = exs + e1;
        o1s[2 * t + 1] = exs;
    }
}

// ---- scan pass 3: element-granular P0 / S1 (stored f16) / S1s ----
__global__ __launch_bounds__(256) void scan_pass3(const f16* __restrict__ h,
                                                  const int* __restrict__ perm,
                                                  const float* __restrict__ gs,
                                                  const float* __restrict__ o0,
                                                  const float* __restrict__ o1,
                                                  const float* __restrict__ o1s,
                                                  f16* __restrict__ P0,
                                                  f16* __restrict__ S1,
                                                  float* __restrict__ S1s) {
    const int k = blockIdx.x, c = threadIdx.x;
    const int base = k * CHROWS;
    __shared__ int p[CHROWS];
    __shared__ float wl[CHROWS];
    if (c < CHROWS) {
        p[c] = perm[base + c];
        wl[c] = expf(gs[base + c] - gs[NROWS - 1]);
    }
    __syncthreads();
    float run0 = o0[k * FOUT + c];
    for (int r = 0; r < CHROWS; ++r) {
        P0[(size_t)(base + r) * FOUT + c] = (f16)run0;
        run0 += (float)h[(size_t)p[r] * FOUT + c];
    }
    float run1 = o1[k * FOUT + c];
    for (int r = CHROWS - 1; r >= 0; --r) {
        run1 += wl[r] * (float)h[(size_t)p[r] * FOUT + c];
        S1[(size_t)(base + r) * FOUT + c] = (f16)run1;
    }
    if (c == 0) {
        float rs = o1s[k];
        for (int r = CHROWS - 1; r >= 0; --r) { rs += wl[r]; S1s[base + r] = rs; }
    }
    if (k == NCHUNK - 1) {
        P0[(size_t)NROWS * FOUT + c] = (f16)run0;   // total column sum
        S1[(size_t)NROWS * FOUT + c] = (f16)0.f;
        if (c == 0) S1s[NROWS] = 0.f;
    }
}

// ---- final: streaming combine + ELU, 4 rows/block ----
__global__ __launch_bounds__(256) void final_kernel(const float* __restrict__ f,
                                                    const float* __restrict__ gs,
                                                    const int* __restrict__ n0arr,
                                                    const f16* __restrict__ P0,
                                                    const f16* __restrict__ S1,
                                                    const float* __restrict__ S1s,
                                                    float* __restrict__ out) {
    const int b = blockIdx.x, c = threadIdx.x;
    const float gm = gs[NROWS - 1];
#pragma unroll
    for (int rr = 0; rr < 4; ++rr) {
        const int i = b * 4 + rr;
        const float fi = f[i];
        const int n0 = n0arr[i];
        const float m = fmaxf(0.f, fi + gm);
        const float A = expf(-m);
        const float B = expf(fi + gm - m);
        const float denom = A * (float)n0 + B * S1s[n0];
        const float numer = A * (float)P0[(size_t)n0 * FOUT + c]
                          + B * (float)S1[(size_t)n0 * FOUT + c];
        const float v = numer / denom;
        out[(size_t)i * FOUT + c] = v > 0.f ? v : expm1f(v);
    }
}

extern "C" void kernel_launch(void* const* d_in, const int* in_sizes, int n_in,
                              void* d_out, int out_size, void* d_ws, size_t ws_size,
                              hipStream_t stream) {
    (void)in_sizes; (void)n_in; (void)out_size; (void)ws_size;
    const float* x = (const float*)d_in[0];
    const float* W = (const float*)d_in[1];
    const float* a = (const float*)d_in[2];
    float* out = (float*)d_out;

    char* ws = (char*)d_ws;
    size_t off = 0;
    auto alloc = [&](size_t bytes) -> void* {
        void* p = ws + off;
        off += (bytes + 255) & ~(size_t)255;
        return p;
    };
    f16*   Wt   = (f16*)alloc((size_t)FOUT * FIN * 2);
    f16*   h    = (f16*)alloc((size_t)NROWS * FOUT * 2);
    f16*   P0   = (f16*)alloc((size_t)(NROWS + 1) * FOUT * 2);
    f16*   S1   = (f16*)alloc((size_t)(NROWS + 1) * FOUT * 2);
    float* fg   = (float*)alloc(2 * NROWS * 4);
    float* f    = fg;
    float* g    = fg + NROWS;
    float* gs   = (float*)alloc(NROWS * 4);
    int*   perm = (int*)alloc(NROWS * 4);
    int*   n0arr= (int*)alloc(NROWS * 4);
    float* c0   = (float*)alloc(NCHUNK * FOUT * 4);
    float* c1   = (float*)alloc(NCHUNK * FOUT * 4);
    float* o0   = (float*)alloc(NCHUNK * FOUT * 4);
    float* o1   = (float*)alloc(NCHUNK * FOUT * 4);
    float* c1s  = (float*)alloc(NCHUNK * 4);
    float* o1s  = (float*)alloc(NCHUNK * 4);
    float* S1s  = (float*)alloc((NROWS + 1) * 4);

    prep_wt<<<256, 256, 0, stream>>>(W, Wt, fg);
    gemm_fg<<<dim3(FOUT / 128, NROWS / 64), 512, 0, stream>>>(x, Wt, a, h, f, g);
    rank_scatter<<<NROWS / 16, 256, 0, stream>>>(g, gs, perm);
    scan_pass1<<<NCHUNK + 32, 256, 0, stream>>>(h, perm, gs, f, c0, c1, c1s, n0arr);
    scan_pass2<<<513, 256, 0, stream>>>(c0, c1, c1s, o0, o1, o1s);
    scan_pass3<<<NCHUNK, 256, 0, stream>>>(h, perm, gs, o0, o1, o1s, P0, S1, S1s);
    final_kernel<<<NROWS / 4, 256, 0, stream>>>(f, gs, n0arr, P0, S1, S1s, out);
}